// Round 3
// baseline (3295.761 us; speedup 1.0000x reference)
//
#include <hip/hip_runtime.h>
#include <hip/hip_bf16.h>

#define Bn 64
#define Ln 2048
#define Hn 128
#define Vn 32000
#define THn 256            // 2*H
#define LAMBDA_ (1.0f/2048.0f)
#define CC 32              // scan chunk size
#define NCH (Ln/CC)        // 64 chunks

// ---------------------------------------------------------------------------
// Phase 1: embed gather + FF1+FF2 (fused over o-quarters) + residual + LN +
// k-projection. 64 tokens per block, 4 waves = o/i ranges. LDS ~52KB so
// 3 blocks/CU (v1 was ~100KB -> 1 block/CU, latency-bound).
// Weights are wave-uniform float4 row reads (scalar loads), fragments held in
// registers, 32 FMAs per 8-load batch.
// ---------------------------------------------------------------------------
__global__ __launch_bounds__(256, 3) void p1_fused(
    const int* __restrict__ seq,
    const float* __restrict__ embed_w,
    const float* __restrict__ ff_w1, const float* __restrict__ ff_b1,
    const float* __restrict__ ff_w2, const float* __restrict__ ff_b2,
    const float* __restrict__ ln_g, const float* __restrict__ ln_b,
    const float* __restrict__ kp_w,
    float* __restrict__ kn_all, float* __restrict__ norm_all)
{
  __shared__ __align__(16) float h_l[128*64];   // [feature][token]
  __shared__ __align__(16) float u_q[64*64];    // one o-quarter of u, [o][token]
  __shared__ float part1[256], part2[256], rinv_l[64];
  __shared__ int sid[64];

  const int tid  = threadIdx.x;
  const int lane = tid & 63;                                  // token
  const int w    = __builtin_amdgcn_readfirstlane(tid >> 6);  // wave (uniform)
  const int tile0 = blockIdx.x * 64;

  if (tid < 64) sid[tid] = seq[tile0 + tid];
  __syncthreads();

  { // embed gather -> h_l[j][t]
    const int t = tid >> 2, part = tid & 3;
    const float4* erow =
        reinterpret_cast<const float4*>(embed_w + (size_t)sid[t]*Hn) + part*8;
    #pragma unroll
    for (int c = 0; c < 8; ++c) {
      float4 v = erow[c];
      int j = part*32 + c*4;
      h_l[(j+0)*64+t]=v.x; h_l[(j+1)*64+t]=v.y;
      h_l[(j+2)*64+t]=v.z; h_l[(j+3)*64+t]=v.w;
    }
  }
  __syncthreads();

  float x[32];
  #pragma unroll
  for (int ii=0;ii<32;++ii) x[ii]=0.f;

  // ---- FF1 + FF2, fused over 4 o-quarters of 64 ----
  #pragma unroll 1
  for (int p=0;p<4;++p) {
    float u[16];
    #pragma unroll
    for (int oi=0;oi<16;++oi) u[oi] = ff_b1[p*64 + w*16 + oi];
    #pragma unroll 1
    for (int kq=0;kq<4;++kq) {
      float hv[32];
      #pragma unroll
      for (int j=0;j<32;++j) hv[j] = h_l[(kq*32+j)*64 + lane];
      #pragma unroll
      for (int oi=0;oi<16;++oi) {
        const float4* w4 = reinterpret_cast<const float4*>(
            ff_w1 + (size_t)(p*64 + w*16 + oi)*Hn + kq*32);
        float a0=0,a1=0,a2=0,a3=0;
        #pragma unroll
        for (int q=0;q<8;++q) {
          float4 wv = w4[q];
          a0 += hv[q*4+0]*wv.x; a1 += hv[q*4+1]*wv.y;
          a2 += hv[q*4+2]*wv.z; a3 += hv[q*4+3]*wv.w;
        }
        u[oi] += (a0+a1)+(a2+a3);
      }
    }
    if (p) __syncthreads();          // prev pass FF2 done before u_q overwrite
    #pragma unroll
    for (int oi=0;oi<16;++oi) u_q[(w*16+oi)*64 + lane] = fmaxf(u[oi], 0.f);
    __syncthreads();
    #pragma unroll 1
    for (int og=0;og<2;++og) {
      float uv[32];
      #pragma unroll
      for (int j=0;j<32;++j) uv[j] = u_q[(og*32+j)*64 + lane];
      #pragma unroll
      for (int ii=0;ii<32;++ii) {
        const float4* w4 = reinterpret_cast<const float4*>(
            ff_w2 + (size_t)(w*32+ii)*THn + p*64 + og*32);
        float a0=0,a1=0,a2=0,a3=0;
        #pragma unroll
        for (int q=0;q<8;++q) {
          float4 wv = w4[q];
          a0 += uv[q*4+0]*wv.x; a1 += uv[q*4+1]*wv.y;
          a2 += uv[q*4+2]*wv.z; a3 += uv[q*4+3]*wv.w;
        }
        x[ii] += (a0+a1)+(a2+a3);
      }
    }
  }

  // ---- residual + LayerNorm ----
  const int i0 = w*32;
  float s1=0.f, s2=0.f;
  #pragma unroll
  for (int ii=0;ii<32;++ii) {
    x[ii] += ff_b2[i0+ii] + h_l[(i0+ii)*64 + lane];
    s1 += x[ii]; s2 += x[ii]*x[ii];
  }
  part1[w*64+lane]=s1; part2[w*64+lane]=s2;
  __syncthreads();
  float mu=0.f, ms=0.f;
  #pragma unroll
  for (int ww=0;ww<4;++ww) { mu += part1[ww*64+lane]; ms += part2[ww*64+lane]; }
  mu *= (1.0f/128.0f); ms *= (1.0f/128.0f);
  const float rstd = rsqrtf(ms - mu*mu + 1e-5f);
  #pragma unroll
  for (int ii=0;ii<32;++ii)
    h_l[(i0+ii)*64 + lane] = (x[ii]-mu)*rstd*ln_g[i0+ii] + ln_b[i0+ii];
  __syncthreads();

  // ---- k projection ----
  float kacc[32];
  #pragma unroll
  for (int oo=0;oo<32;++oo) kacc[oo]=0.f;
  #pragma unroll 1
  for (int ib=0;ib<4;++ib) {
    float hv[32];
    #pragma unroll
    for (int j=0;j<32;++j) hv[j] = h_l[(ib*32+j)*64 + lane];
    #pragma unroll
    for (int oo=0;oo<32;++oo) {
      const float4* w4 = reinterpret_cast<const float4*>(
          kp_w + (size_t)(i0+oo)*Hn + ib*32);
      float a0=0,a1=0,a2=0,a3=0;
      #pragma unroll
      for (int q=0;q<8;++q) {
        float4 wv = w4[q];
        a0 += hv[q*4+0]*wv.x; a1 += hv[q*4+1]*wv.y;
        a2 += hv[q*4+2]*wv.z; a3 += hv[q*4+3]*wv.w;
      }
      kacc[oo] += (a0+a1)+(a2+a3);
    }
  }
  float ps=0.f;
  #pragma unroll
  for (int oo=0;oo<32;++oo) ps += kacc[oo]*kacc[oo];
  part1[w*64+lane]=ps;
  __syncthreads();
  if (tid<64) {
    float nn = part1[tid]+part1[64+tid]+part1[128+tid]+part1[192+tid];
    float nrm = sqrtf(nn);
    norm_all[tile0+tid]=nrm;
    rinv_l[tid]=1.0f/fmaxf(nrm,1e-12f);
  }
  __syncthreads();
  const float riv = rinv_l[lane];
  float4* dst = reinterpret_cast<float4*>(kn_all + (size_t)(tile0+lane)*Hn + w*32);
  #pragma unroll
  for (int q=0;q<8;++q)
    dst[q] = make_float4(kacc[q*4]*riv, kacc[q*4+1]*riv,
                         kacc[q*4+2]*riv, kacc[q*4+3]*riv);
}

// ---------------------------------------------------------------------------
// Phase 2: chunked (WY) gated delta-rule scan, C=32. One block per batch.
// M in VGPRs (thread = 4 rows x 16 cols). Per chunk: Gram + VP0=M*Kn^T on all
// 4 waves, a single-wave serial d-recurrence (no barriers), rank-32 M update.
// kn LDS layout: [t][group-of-16 padded to 20]; vpd [t][i +4 pad at 64].
// ---------------------------------------------------------------------------
__global__ __launch_bounds__(256) void p2_scan(
    const float* __restrict__ kn_all, const float* __restrict__ norm_all,
    float* __restrict__ read_ws)
{
  const int tid  = threadIdx.x;
  const int lane = tid & 63;
  const int wv   = tid >> 6;
  const int ib   = tid >> 3;      // 0..31 -> rows 4ib..4ib+3
  const int cb   = tid & 7;       // 0..7  -> cols 16cb..16cb+15
  const int b    = blockIdx.x;

  __shared__ __align__(16) float kn_l[CC*164];
  __shared__ __align__(16) float vpd [CC*132];   // vp0, later a_s*d_s (per t)
  __shared__ __align__(16) float adT [128*34];   // [i][s] transposed a_s*d_s
  __shared__ __align__(16) float Gt  [CC*36];    // Gt[t][s] = kn_s.kn_t (0 if s>=t)
  __shared__ float nrm_l[CC], a_l[CC];

  float M[4][16];
  #pragma unroll
  for (int r=0;r<4;++r)
    #pragma unroll
    for (int c=0;c<16;++c) M[r][c]=0.f;

  const float* knb = kn_all + (size_t)b*Ln*Hn;
  const float* nb  = norm_all + (size_t)b*Ln;
  const int rbase  = 4*ib + ((ib>=16)?4:0);

  for (int i=tid; i<128*34; i+=256) adT[i]=0.f;  // stale-read safety (x0 mask)

  { // stage chunk 0: [t][i] -> padded groups
    const int t = tid>>3, ig = tid&7;
    const float4* src = reinterpret_cast<const float4*>(knb + t*Hn + ig*16);
    float* d0 = &kn_l[t*164 + ig*20];
    float4 v0=src[0], v1=src[1], v2=src[2], v3=src[3];
    *reinterpret_cast<float4*>(d0+0)=v0;  *reinterpret_cast<float4*>(d0+4)=v1;
    *reinterpret_cast<float4*>(d0+8)=v2;  *reinterpret_cast<float4*>(d0+12)=v3;
    if (tid<CC) nrm_l[tid]=nb[tid];
  }
  __syncthreads();

  #pragma unroll 1
  for (int ch=0; ch<NCH; ++ch) {
    // prefetch next chunk into registers (latency off critical path)
    float4 pf0,pf1,pf2,pf3; float pfn=0.f;
    const bool havenext = (ch+1 < NCH);
    if (havenext) {
      const float4* src = reinterpret_cast<const float4*>(
          knb + (size_t)(ch+1)*CC*Hn + tid*16);
      pf0=src[0]; pf1=src[1]; pf2=src[2]; pf3=src[3];
      if (tid<CC) pfn = nb[(ch+1)*CC + tid];
    }

    { // ---- Gram: Gt[t][s] (zero for s>=t) ----
      const int t = tid>>3, sb = tid&7;
      float g0=0,g1=0,g2=0,g3=0;
      #pragma unroll 4
      for (int k4=0;k4<32;++k4) {
        const int ka = (k4>>2)*20 + (k4&3)*4;
        float4 ft = *reinterpret_cast<const float4*>(&kn_l[t*164+ka]);
        float4 f0 = *reinterpret_cast<const float4*>(&kn_l[(4*sb+0)*164+ka]);
        float4 f1 = *reinterpret_cast<const float4*>(&kn_l[(4*sb+1)*164+ka]);
        float4 f2 = *reinterpret_cast<const float4*>(&kn_l[(4*sb+2)*164+ka]);
        float4 f3 = *reinterpret_cast<const float4*>(&kn_l[(4*sb+3)*164+ka]);
        g0 += ft.x*f0.x+ft.y*f0.y+ft.z*f0.z+ft.w*f0.w;
        g1 += ft.x*f1.x+ft.y*f1.y+ft.z*f1.z+ft.w*f1.w;
        g2 += ft.x*f2.x+ft.y*f2.y+ft.z*f2.z+ft.w*f2.w;
        g3 += ft.x*f3.x+ft.y*f3.y+ft.z*f3.z+ft.w*f3.w;
      }
      if (4*sb+0 >= t) g0=0.f;
      if (4*sb+1 >= t) g1=0.f;
      if (4*sb+2 >= t) g2=0.f;
      if (4*sb+3 >= t) g3=0.f;
      *reinterpret_cast<float4*>(&Gt[t*36+4*sb]) = make_float4(g0,g1,g2,g3);
    }

    // ---- Phase A: vp0 = M * Kn^T (partial per cb, shfl-reduced) ----
    #pragma unroll 1
    for (int tb=0;tb<2;++tb) {
      float acc[4][16];
      #pragma unroll
      for (int r=0;r<4;++r)
        #pragma unroll
        for (int tt=0;tt<16;++tt) acc[r][tt]=0.f;
      #pragma unroll
      for (int tt=0;tt<16;++tt) {
        const int t = tb*16+tt;
        float f[16];
        #pragma unroll
        for (int q=0;q<4;++q) {
          float4 v = *reinterpret_cast<const float4*>(&kn_l[t*164 + cb*20 + 4*q]);
          f[4*q]=v.x; f[4*q+1]=v.y; f[4*q+2]=v.z; f[4*q+3]=v.w;
        }
        #pragma unroll
        for (int c=0;c<16;++c) {
          acc[0][tt] += M[0][c]*f[c];
          acc[1][tt] += M[1][c]*f[c];
          acc[2][tt] += M[2][c]*f[c];
          acc[3][tt] += M[3][c]*f[c];
        }
      }
      #pragma unroll
      for (int r=0;r<4;++r)
        #pragma unroll
        for (int tt=0;tt<16;++tt) {
          float v = acc[r][tt];
          v += __shfl_xor(v,1); v += __shfl_xor(v,2); v += __shfl_xor(v,4);
          acc[r][tt]=v;
        }
      #pragma unroll
      for (int tt=0;tt<16;++tt) {
        if ((tt>>1)==cb) {
          const int t = tb*16+tt;
          *reinterpret_cast<float4*>(&vpd[t*132 + rbase]) =
              make_float4(acc[0][tt],acc[1][tt],acc[2][tt],acc[3][tt]);
        }
      }
    }
    __syncthreads();                       // B2: vpd + Gt ready

    // ---- serial d-recurrence (wave 0 only, no barriers) ----
    if (wv==0) {
      const int sw0 = (lane>>4)*20 + (lane&15);
      const int sw1 = sw0 + 80;            // component 64+lane
      #pragma unroll 1
      for (int t=0;t<CC;++t) {
        const float nrm = nrm_l[t];
        const float kn0 = kn_l[t*164 + sw0];
        const float kn1 = kn_l[t*164 + sw1];
        float acc0 = nrm*kn0 - vpd[t*132 + lane];
        float acc1 = nrm*kn1 - vpd[t*132 + 68 + lane];
        #pragma unroll
        for (int s4=0;s4<8;++s4) {         // Gt zeros mask s>=t (adT finite)
          float4 g = *reinterpret_cast<const float4*>(&Gt[t*36 + 4*s4]);
          const float* p0 = &adT[lane*34 + 4*s4];
          const float* p1 = &adT[(64+lane)*34 + 4*s4];
          float2 x0a = *reinterpret_cast<const float2*>(p0);
          float2 x0b = *reinterpret_cast<const float2*>(p0+2);
          float2 x1a = *reinterpret_cast<const float2*>(p1);
          float2 x1b = *reinterpret_cast<const float2*>(p1+2);
          acc0 -= g.x*x0a.x + g.y*x0a.y + g.z*x0b.x + g.w*x0b.y;
          acc1 -= g.x*x1a.x + g.y*x1a.y + g.z*x1b.x + g.w*x1b.y;
        }
        float sq = acc0*acc0 + acc1*acc1;
        sq += __shfl_xor(sq,32); sq += __shfl_xor(sq,16); sq += __shfl_xor(sq,8);
        sq += __shfl_xor(sq,4);  sq += __shfl_xor(sq,2);  sq += __shfl_xor(sq,1);
        if (ch==NCH-1 && t==CC-1) {
          // query step: read = nrm * vp, vp = k - d
          read_ws[b*Hn + lane]      = nrm*(nrm*kn0 - acc0);
          read_ws[b*Hn + 64 + lane] = nrm*(nrm*kn1 - acc1);
        } else {
          const float at = (sqrtf(sq) >= 0.4f*nrm) ? LAMBDA_ : 0.f;
          const float ad0 = at*acc0, ad1 = at*acc1;
          vpd[t*132 + lane]      = ad0;    // overwrite vp0 with a*d
          vpd[t*132 + 68 + lane] = ad1;
          adT[lane*34 + t]       = ad0;
          adT[(64+lane)*34 + t]  = ad1;
          if (lane==0) a_l[t] = at;
        }
      }
    }
    __syncthreads();                       // B3
    if (ch==NCH-1) break;

    // ---- Phase E: M += AD * Kn ----
    #pragma unroll 1
    for (int s=0;s<CC;++s) {
      const float as = a_l[s];
      if (as != 0.f) {                     // uniform branch (gate off -> skip)
        float4 ad = *reinterpret_cast<const float4*>(&vpd[s*132 + rbase]);
        float f[16];
        #pragma unroll
        for (int q=0;q<4;++q) {
          float4 v = *reinterpret_cast<const float4*>(&kn_l[s*164 + cb*20 + 4*q]);
          f[4*q]=v.x; f[4*q+1]=v.y; f[4*q+2]=v.z; f[4*q+3]=v.w;
        }
        #pragma unroll
        for (int c=0;c<16;++c) {
          M[0][c] += ad.x*f[c];
          M[1][c] += ad.y*f[c];
          M[2][c] += ad.z*f[c];
          M[3][c] += ad.w*f[c];
        }
      }
    }
    __syncthreads();                       // B4: kn_l free to overwrite
    { // stage prefetched chunk
      const int t = tid>>3, ig = tid&7;
      float* d0 = &kn_l[t*164 + ig*20];
      *reinterpret_cast<float4*>(d0+0)=pf0;  *reinterpret_cast<float4*>(d0+4)=pf1;
      *reinterpret_cast<float4*>(d0+8)=pf2;  *reinterpret_cast<float4*>(d0+12)=pf3;
      if (tid<CC) nrm_l[tid]=pfn;
    }
    __syncthreads();                       // B5
  }
}

// ---------------------------------------------------------------------------
// Phase 3a: o1 = read @ rp_w^T + rp_b   (tiny)
// ---------------------------------------------------------------------------
__global__ __launch_bounds__(128) void p3a(
    const float* __restrict__ read_ws, const float* __restrict__ rp_w,
    const float* __restrict__ rp_b, float* __restrict__ o1_ws)
{
  __shared__ float rd[128];
  const int b = blockIdx.x, t = threadIdx.x;
  rd[t] = read_ws[b*Hn + t];
  __syncthreads();
  float acc = rp_b[t];
  const float* wr = rp_w + t*Hn;
  #pragma unroll 4
  for (int i = 0; i < Hn; ++i) acc += rd[i]*wr[i];
  o1_ws[b*Hn + t] = acc;
}

// ---------------------------------------------------------------------------
// Phase 3b: out = o1 @ out_w^T + out_b. Thread = one vocab column, 64 batches
// in registers; out_w streamed once.
// ---------------------------------------------------------------------------
__global__ __launch_bounds__(256) void p3b(
    const float* __restrict__ o1_ws, const float* __restrict__ out_w,
    const float* __restrict__ out_b, float* __restrict__ out)
{
  __shared__ __align__(16) float o1[8192];       // [64][128]
  const int tid = threadIdx.x;
  #pragma unroll
  for (int c = 0; c < 32; ++c) o1[c*256+tid] = o1_ws[c*256+tid];
  __syncthreads();
  const int v = blockIdx.x*256 + tid;            // 125*256 == 32000
  float acc[64];
  const float ob = out_b[v];
  #pragma unroll
  for (int bb = 0; bb < 64; ++bb) acc[bb] = ob;
  const float4* wrow = reinterpret_cast<const float4*>(out_w + (size_t)v*Hn);
  #pragma unroll 1
  for (int r4 = 0; r4 < 32; ++r4) {
    const float4 wv = wrow[r4];
    #pragma unroll
    for (int bb = 0; bb < 64; ++bb) {
      const float4 ov = *reinterpret_cast<const float4*>(&o1[bb*Hn + r4*4]);
      acc[bb] += wv.x*ov.x + wv.y*ov.y + wv.z*ov.z + wv.w*ov.w;
    }
  }
  #pragma unroll
  for (int bb = 0; bb < 64; ++bb) out[(size_t)bb*Vn + v] = acc[bb];
}

// ---------------------------------------------------------------------------
extern "C" void kernel_launch(void* const* d_in, const int* in_sizes, int n_in,
                              void* d_out, int out_size, void* d_ws, size_t ws_size,
                              hipStream_t stream)
{
  const int*   seq     = (const int*)  d_in[0];
  const float* embed_w = (const float*)d_in[1];
  const float* ff_w1   = (const float*)d_in[2];
  const float* ff_b1   = (const float*)d_in[3];
  const float* ff_w2   = (const float*)d_in[4];
  const float* ff_b2   = (const float*)d_in[5];
  const float* ln_g    = (const float*)d_in[6];
  const float* ln_b    = (const float*)d_in[7];
  const float* kp_w    = (const float*)d_in[8];
  const float* rp_w    = (const float*)d_in[9];
  const float* rp_b    = (const float*)d_in[10];
  const float* out_w   = (const float*)d_in[11];
  const float* out_b   = (const float*)d_in[12];

  float* ws       = (float*)d_ws;
  float* kn_all   = ws;                               // B*L*H
  float* norm_all = ws + (size_t)Bn*Ln*Hn;            // B*L
  float* read_ws  = norm_all + (size_t)Bn*Ln;         // B*H
  float* o1_ws    = read_ws + Bn*Hn;                  // B*H

  p1_fused<<<dim3(2048), dim3(256), 0, stream>>>(
      seq, embed_w, ff_w1, ff_b1, ff_w2, ff_b2, ln_g, ln_b, kp_w, kn_all, norm_all);
  p2_scan<<<dim3(64), dim3(256), 0, stream>>>(kn_all, norm_all, read_ws);
  p3a<<<dim3(64), dim3(128), 0, stream>>>(read_ws, rp_w, rp_b, o1_ws);
  p3b<<<dim3(125), dim3(256), 0, stream>>>(o1_ws, out_w, out_b, (float*)d_out);
}

// Round 4
// 2262.652 us; speedup vs baseline: 1.4566x; 1.4566x over previous
//
#include <hip/hip_runtime.h>
#include <hip/hip_bf16.h>

#define Bn 64
#define Ln 2048
#define Hn 128
#define Vn 32000
#define THn 256            // 2*H
#define LAMBDA_ (1.0f/2048.0f)
#define CC 32              // scan chunk size
#define NCH (Ln/CC)        // 64 chunks

__device__ __forceinline__ float rdlane(float v, int s) {
  return __int_as_float(__builtin_amdgcn_readlane(__float_as_int(v), s));
}

// ---------------------------------------------------------------------------
// Phase 1: embed gather + FF1+FF2 (fused over o-quarters) + residual + LN +
// k-projection. 64 tokens per block, 4 waves. LDS ~52KB -> 3 blocks/CU.
// (unchanged from r3)
// ---------------------------------------------------------------------------
__global__ __launch_bounds__(256, 3) void p1_fused(
    const int* __restrict__ seq,
    const float* __restrict__ embed_w,
    const float* __restrict__ ff_w1, const float* __restrict__ ff_b1,
    const float* __restrict__ ff_w2, const float* __restrict__ ff_b2,
    const float* __restrict__ ln_g, const float* __restrict__ ln_b,
    const float* __restrict__ kp_w,
    float* __restrict__ kn_all, float* __restrict__ norm_all)
{
  __shared__ __align__(16) float h_l[128*64];   // [feature][token]
  __shared__ __align__(16) float u_q[64*64];    // one o-quarter of u, [o][token]
  __shared__ float part1[256], part2[256], rinv_l[64];
  __shared__ int sid[64];

  const int tid  = threadIdx.x;
  const int lane = tid & 63;                                  // token
  const int w    = __builtin_amdgcn_readfirstlane(tid >> 6);  // wave (uniform)
  const int tile0 = blockIdx.x * 64;

  if (tid < 64) sid[tid] = seq[tile0 + tid];
  __syncthreads();

  { // embed gather -> h_l[j][t]
    const int t = tid >> 2, part = tid & 3;
    const float4* erow =
        reinterpret_cast<const float4*>(embed_w + (size_t)sid[t]*Hn) + part*8;
    #pragma unroll
    for (int c = 0; c < 8; ++c) {
      float4 v = erow[c];
      int j = part*32 + c*4;
      h_l[(j+0)*64+t]=v.x; h_l[(j+1)*64+t]=v.y;
      h_l[(j+2)*64+t]=v.z; h_l[(j+3)*64+t]=v.w;
    }
  }
  __syncthreads();

  float x[32];
  #pragma unroll
  for (int ii=0;ii<32;++ii) x[ii]=0.f;

  // ---- FF1 + FF2, fused over 4 o-quarters of 64 ----
  #pragma unroll 1
  for (int p=0;p<4;++p) {
    float u[16];
    #pragma unroll
    for (int oi=0;oi<16;++oi) u[oi] = ff_b1[p*64 + w*16 + oi];
    #pragma unroll 1
    for (int kq=0;kq<4;++kq) {
      float hv[32];
      #pragma unroll
      for (int j=0;j<32;++j) hv[j] = h_l[(kq*32+j)*64 + lane];
      #pragma unroll
      for (int oi=0;oi<16;++oi) {
        const float4* w4 = reinterpret_cast<const float4*>(
            ff_w1 + (size_t)(p*64 + w*16 + oi)*Hn + kq*32);
        float a0=0,a1=0,a2=0,a3=0;
        #pragma unroll
        for (int q=0;q<8;++q) {
          float4 wv = w4[q];
          a0 += hv[q*4+0]*wv.x; a1 += hv[q*4+1]*wv.y;
          a2 += hv[q*4+2]*wv.z; a3 += hv[q*4+3]*wv.w;
        }
        u[oi] += (a0+a1)+(a2+a3);
      }
    }
    if (p) __syncthreads();          // prev pass FF2 done before u_q overwrite
    #pragma unroll
    for (int oi=0;oi<16;++oi) u_q[(w*16+oi)*64 + lane] = fmaxf(u[oi], 0.f);
    __syncthreads();
    #pragma unroll 1
    for (int og=0;og<2;++og) {
      float uv[32];
      #pragma unroll
      for (int j=0;j<32;++j) uv[j] = u_q[(og*32+j)*64 + lane];
      #pragma unroll
      for (int ii=0;ii<32;++ii) {
        const float4* w4 = reinterpret_cast<const float4*>(
            ff_w2 + (size_t)(w*32+ii)*THn + p*64 + og*32);
        float a0=0,a1=0,a2=0,a3=0;
        #pragma unroll
        for (int q=0;q<8;++q) {
          float4 wv = w4[q];
          a0 += uv[q*4+0]*wv.x; a1 += uv[q*4+1]*wv.y;
          a2 += uv[q*4+2]*wv.z; a3 += uv[q*4+3]*wv.w;
        }
        x[ii] += (a0+a1)+(a2+a3);
      }
    }
  }

  // ---- residual + LayerNorm ----
  const int i0 = w*32;
  float s1=0.f, s2=0.f;
  #pragma unroll
  for (int ii=0;ii<32;++ii) {
    x[ii] += ff_b2[i0+ii] + h_l[(i0+ii)*64 + lane];
    s1 += x[ii]; s2 += x[ii]*x[ii];
  }
  part1[w*64+lane]=s1; part2[w*64+lane]=s2;
  __syncthreads();
  float mu=0.f, ms=0.f;
  #pragma unroll
  for (int ww=0;ww<4;++ww) { mu += part1[ww*64+lane]; ms += part2[ww*64+lane]; }
  mu *= (1.0f/128.0f); ms *= (1.0f/128.0f);
  const float rstd = rsqrtf(ms - mu*mu + 1e-5f);
  #pragma unroll
  for (int ii=0;ii<32;++ii)
    h_l[(i0+ii)*64 + lane] = (x[ii]-mu)*rstd*ln_g[i0+ii] + ln_b[i0+ii];
  __syncthreads();

  // ---- k projection ----
  float kacc[32];
  #pragma unroll
  for (int oo=0;oo<32;++oo) kacc[oo]=0.f;
  #pragma unroll 1
  for (int ib=0;ib<4;++ib) {
    float hv[32];
    #pragma unroll
    for (int j=0;j<32;++j) hv[j] = h_l[(ib*32+j)*64 + lane];
    #pragma unroll
    for (int oo=0;oo<32;++oo) {
      const float4* w4 = reinterpret_cast<const float4*>(
          kp_w + (size_t)(i0+oo)*Hn + ib*32);
      float a0=0,a1=0,a2=0,a3=0;
      #pragma unroll
      for (int q=0;q<8;++q) {
        float4 wv = w4[q];
        a0 += hv[q*4+0]*wv.x; a1 += hv[q*4+1]*wv.y;
        a2 += hv[q*4+2]*wv.z; a3 += hv[q*4+3]*wv.w;
      }
      kacc[oo] += (a0+a1)+(a2+a3);
    }
  }
  float ps=0.f;
  #pragma unroll
  for (int oo=0;oo<32;++oo) ps += kacc[oo]*kacc[oo];
  part1[w*64+lane]=ps;
  __syncthreads();
  if (tid<64) {
    float nn = part1[tid]+part1[64+tid]+part1[128+tid]+part1[192+tid];
    float nrm = sqrtf(nn);
    norm_all[tile0+tid]=nrm;
    rinv_l[tid]=1.0f/fmaxf(nrm,1e-12f);
  }
  __syncthreads();
  const float riv = rinv_l[lane];
  float4* dst = reinterpret_cast<float4*>(kn_all + (size_t)(tile0+lane)*Hn + w*32);
  #pragma unroll
  for (int q=0;q<8;++q)
    dst[q] = make_float4(kacc[q*4]*riv, kacc[q*4+1]*riv,
                         kacc[q*4+2]*riv, kacc[q*4+3]*riv);
}

// ---------------------------------------------------------------------------
// Phase 2: chunked WY gated delta-rule scan, C=32. One block per batch.
// M in VGPRs (thread = 4 rows x 16 cols). Serial d-recurrence is REGISTER-
// RESIDENT on wave 0: ad vectors in VGPRs (static unroll), G scalars via
// v_readlane from a conflict-free preload. Zero LDS in the serial dep chain
// beyond 4 b32 reads/step.
// ---------------------------------------------------------------------------
__global__ __launch_bounds__(256) void p2_scan(
    const float* __restrict__ kn_all, const float* __restrict__ norm_all,
    float* __restrict__ read_ws)
{
  const int tid  = threadIdx.x;
  const int lane = tid & 63;
  const int wv   = tid >> 6;
  const int ib   = tid >> 3;      // 0..31 -> rows 4ib..4ib+3
  const int cb   = tid & 7;       // 0..7  -> cols 16cb..16cb+15
  const int b    = blockIdx.x;

  __shared__ __align__(16) float kn_l[CC*164];   // [t][8 groups of 16, pad to 20]
  __shared__ __align__(16) float vpd [CC*132];   // [t][i] vp0, then a_t*d_t
  __shared__ __align__(16) float Gt  [CC*36];    // Gt[t][s] = kn_s . kn_t
  __shared__ float nrm_l[CC];

  float M[4][16];
  #pragma unroll
  for (int r=0;r<4;++r)
    #pragma unroll
    for (int c=0;c<16;++c) M[r][c]=0.f;

  const float* knb = kn_all + (size_t)b*Ln*Hn;
  const float* nb  = norm_all + (size_t)b*Ln;

  { // stage chunk 0
    const int t = tid>>3, ig = tid&7;
    const float4* src = reinterpret_cast<const float4*>(knb + t*Hn + ig*16);
    float* d0 = &kn_l[t*164 + ig*20];
    float4 v0=src[0], v1=src[1], v2=src[2], v3=src[3];
    *reinterpret_cast<float4*>(d0+0)=v0;  *reinterpret_cast<float4*>(d0+4)=v1;
    *reinterpret_cast<float4*>(d0+8)=v2;  *reinterpret_cast<float4*>(d0+12)=v3;
    if (tid<CC) nrm_l[tid]=nb[tid];
  }
  __syncthreads();

  #pragma unroll 1
  for (int ch=0; ch<NCH; ++ch) {
    // prefetch next chunk into registers
    float4 pf0,pf1,pf2,pf3; float pfn=0.f;
    const bool havenext = (ch+1 < NCH);
    if (havenext) {
      const float4* src = reinterpret_cast<const float4*>(
          knb + (size_t)(ch+1)*CC*Hn + tid*16);
      pf0=src[0]; pf1=src[1]; pf2=src[2]; pf3=src[3];
      if (tid<CC) pfn = nb[(ch+1)*CC + tid];
    }

    { // ---- Gram: Gt[t][s] full square (upper half unused) ----
      const int t = tid>>3, sb = tid&7;
      float g0=0,g1=0,g2=0,g3=0;
      #pragma unroll 4
      for (int k4=0;k4<32;++k4) {
        const int ka = (k4>>2)*20 + (k4&3)*4;
        float4 ft = *reinterpret_cast<const float4*>(&kn_l[t*164+ka]);
        float4 f0 = *reinterpret_cast<const float4*>(&kn_l[(4*sb+0)*164+ka]);
        float4 f1 = *reinterpret_cast<const float4*>(&kn_l[(4*sb+1)*164+ka]);
        float4 f2 = *reinterpret_cast<const float4*>(&kn_l[(4*sb+2)*164+ka]);
        float4 f3 = *reinterpret_cast<const float4*>(&kn_l[(4*sb+3)*164+ka]);
        g0 += ft.x*f0.x+ft.y*f0.y+ft.z*f0.z+ft.w*f0.w;
        g1 += ft.x*f1.x+ft.y*f1.y+ft.z*f1.z+ft.w*f1.w;
        g2 += ft.x*f2.x+ft.y*f2.y+ft.z*f2.z+ft.w*f2.w;
        g3 += ft.x*f3.x+ft.y*f3.y+ft.z*f3.z+ft.w*f3.w;
      }
      *reinterpret_cast<float4*>(&Gt[t*36+4*sb]) = make_float4(g0,g1,g2,g3);
    }

    // ---- Phase A: vp0 = M * Kn^T ----
    #pragma unroll 1
    for (int tb=0;tb<2;++tb) {
      float acc[4][16];
      #pragma unroll
      for (int r=0;r<4;++r)
        #pragma unroll
        for (int tt=0;tt<16;++tt) acc[r][tt]=0.f;
      #pragma unroll
      for (int tt=0;tt<16;++tt) {
        const int t = tb*16+tt;
        float f[16];
        #pragma unroll
        for (int q=0;q<4;++q) {
          float4 v = *reinterpret_cast<const float4*>(&kn_l[t*164 + cb*20 + 4*q]);
          f[4*q]=v.x; f[4*q+1]=v.y; f[4*q+2]=v.z; f[4*q+3]=v.w;
        }
        #pragma unroll
        for (int c=0;c<16;++c) {
          acc[0][tt] += M[0][c]*f[c];
          acc[1][tt] += M[1][c]*f[c];
          acc[2][tt] += M[2][c]*f[c];
          acc[3][tt] += M[3][c]*f[c];
        }
      }
      #pragma unroll
      for (int r=0;r<4;++r)
        #pragma unroll
        for (int tt=0;tt<16;++tt) {
          float v = acc[r][tt];
          v += __shfl_xor(v,1); v += __shfl_xor(v,2); v += __shfl_xor(v,4);
          acc[r][tt]=v;
        }
      #pragma unroll
      for (int tt=0;tt<16;++tt) {
        if ((tt>>1)==cb) {
          const int t = tb*16+tt;
          *reinterpret_cast<float4*>(&vpd[t*132 + 4*ib]) =
              make_float4(acc[0][tt],acc[1][tt],acc[2][tt],acc[3][tt]);
        }
      }
    }
    __syncthreads();                       // B2: vpd(vp0) + Gt ready

    // ---- serial d-recurrence (wave 0, register-resident) ----
    if (wv==0) {
      float ad0[CC], ad1[CC], gr[CC];
      #pragma unroll
      for (int t=0;t<CC;++t) gr[t] = Gt[t*36 + (lane&31)];   // conflict-free
      const int sw0 = (lane>>4)*20 + (lane&15);
      #pragma unroll
      for (int t=0;t<CC;++t) {
        const float nrm = nrm_l[t];
        const float kn0 = kn_l[t*164 + sw0];        // comp lane
        const float kn1 = kn_l[t*164 + 80 + sw0];   // comp 64+lane
        float a0e = nrm*kn0 - vpd[t*132 + lane];
        float a1e = nrm*kn1 - vpd[t*132 + 64 + lane];
        float a0o = 0.f, a1o = 0.f;
        #pragma unroll
        for (int s=0; s<t; ++s) {                   // static: only s<t emitted
          const float g = rdlane(gr[t], s);         // uniform scalar (SGPR)
          if (s & 1) { a0o -= g*ad0[s]; a1o -= g*ad1[s]; }
          else       { a0e -= g*ad0[s]; a1e -= g*ad1[s]; }
        }
        const float acc0 = a0e + a0o;
        const float acc1 = a1e + a1o;
        float sq = acc0*acc0 + acc1*acc1;
        sq += __shfl_xor(sq,32); sq += __shfl_xor(sq,16); sq += __shfl_xor(sq,8);
        sq += __shfl_xor(sq,4);  sq += __shfl_xor(sq,2);  sq += __shfl_xor(sq,1);
        if (ch==NCH-1 && t==CC-1) {
          // query: read = M@q, q = nrm*kn; M.kn = nrm*kn - d
          read_ws[b*Hn + lane]      = nrm*(nrm*kn0 - acc0);
          read_ws[b*Hn + 64 + lane] = nrm*(nrm*kn1 - acc1);
        } else {
          const float at = (sqrtf(sq) >= 0.4f*nrm) ? LAMBDA_ : 0.f;
          ad0[t] = at*acc0; ad1[t] = at*acc1;
          vpd[t*132 + lane]      = ad0[t];          // publish a*d for E phase
          vpd[t*132 + 64 + lane] = ad1[t];
        }
      }
    }
    __syncthreads();                       // B3: ad ready
    if (ch==NCH-1) break;

    // ---- Phase E: M += sum_s (a_s d_s) x kn_s (ad==0 when gate off) ----
    #pragma unroll 1
    for (int s=0;s<CC;++s) {
      float4 ad = *reinterpret_cast<const float4*>(&vpd[s*132 + 4*ib]);
      float f[16];
      #pragma unroll
      for (int q=0;q<4;++q) {
        float4 v = *reinterpret_cast<const float4*>(&kn_l[s*164 + cb*20 + 4*q]);
        f[4*q]=v.x; f[4*q+1]=v.y; f[4*q+2]=v.z; f[4*q+3]=v.w;
      }
      #pragma unroll
      for (int c=0;c<16;++c) {
        M[0][c] += ad.x*f[c];
        M[1][c] += ad.y*f[c];
        M[2][c] += ad.z*f[c];
        M[3][c] += ad.w*f[c];
      }
    }
    __syncthreads();                       // B4: kn_l free to overwrite
    { // stage prefetched chunk
      const int t = tid>>3, ig = tid&7;
      float* d0 = &kn_l[t*164 + ig*20];
      *reinterpret_cast<float4*>(d0+0)=pf0;  *reinterpret_cast<float4*>(d0+4)=pf1;
      *reinterpret_cast<float4*>(d0+8)=pf2;  *reinterpret_cast<float4*>(d0+12)=pf3;
      if (tid<CC) nrm_l[tid]=pfn;
    }
    __syncthreads();                       // B5
  }
}

// ---------------------------------------------------------------------------
// Phase 3a: o1 = read @ rp_w^T + rp_b   (tiny)
// ---------------------------------------------------------------------------
__global__ __launch_bounds__(128) void p3a(
    const float* __restrict__ read_ws, const float* __restrict__ rp_w,
    const float* __restrict__ rp_b, float* __restrict__ o1_ws)
{
  __shared__ float rd[128];
  const int b = blockIdx.x, t = threadIdx.x;
  rd[t] = read_ws[b*Hn + t];
  __syncthreads();
  float acc = rp_b[t];
  const float* wr = rp_w + t*Hn;
  #pragma unroll 4
  for (int i = 0; i < Hn; ++i) acc += rd[i]*wr[i];
  o1_ws[b*Hn + t] = acc;
}

// ---------------------------------------------------------------------------
// Phase 3b: out = o1 @ out_w^T + out_b
// ---------------------------------------------------------------------------
__global__ __launch_bounds__(256) void p3b(
    const float* __restrict__ o1_ws, const float* __restrict__ out_w,
    const float* __restrict__ out_b, float* __restrict__ out)
{
  __shared__ __align__(16) float o1[8192];       // [64][128]
  const int tid = threadIdx.x;
  #pragma unroll
  for (int c = 0; c < 32; ++c) o1[c*256+tid] = o1_ws[c*256+tid];
  __syncthreads();
  const int v = blockIdx.x*256 + tid;            // 125*256 == 32000
  float acc[64];
  const float ob = out_b[v];
  #pragma unroll
  for (int bb = 0; bb < 64; ++bb) acc[bb] = ob;
  const float4* wrow = reinterpret_cast<const float4*>(out_w + (size_t)v*Hn);
  #pragma unroll 1
  for (int r4 = 0; r4 < 32; ++r4) {
    const float4 wv = wrow[r4];
    #pragma unroll
    for (int bb = 0; bb < 64; ++bb) {
      const float4 ov = *reinterpret_cast<const float4*>(&o1[bb*Hn + r4*4]);
      acc[bb] += wv.x*ov.x + wv.y*ov.y + wv.z*ov.z + wv.w*ov.w;
    }
  }
  #pragma unroll
  for (int bb = 0; bb < 64; ++bb) out[(size_t)bb*Vn + v] = acc[bb];
}

// ---------------------------------------------------------------------------
extern "C" void kernel_launch(void* const* d_in, const int* in_sizes, int n_in,
                              void* d_out, int out_size, void* d_ws, size_t ws_size,
                              hipStream_t stream)
{
  const int*   seq     = (const int*)  d_in[0];
  const float* embed_w = (const float*)d_in[1];
  const float* ff_w1   = (const float*)d_in[2];
  const float* ff_b1   = (const float*)d_in[3];
  const float* ff_w2   = (const float*)d_in[4];
  const float* ff_b2   = (const float*)d_in[5];
  const float* ln_g    = (const float*)d_in[6];
  const float* ln_b    = (const float*)d_in[7];
  const float* kp_w    = (const float*)d_in[8];
  const float* rp_w    = (const float*)d_in[9];
  const float* rp_b    = (const float*)d_in[10];
  const float* out_w   = (const float*)d_in[11];
  const float* out_b   = (const float*)d_in[12];

  float* ws       = (float*)d_ws;
  float* kn_all   = ws;                               // B*L*H
  float* norm_all = ws + (size_t)Bn*Ln*Hn;            // B*L
  float* read_ws  = norm_all + (size_t)Bn*Ln;         // B*H
  float* o1_ws    = read_ws + Bn*Hn;                  // B*H

  p1_fused<<<dim3(2048), dim3(256), 0, stream>>>(
      seq, embed_w, ff_w1, ff_b1, ff_w2, ff_b2, ln_g, ln_b, kp_w, kn_all, norm_all);
  p2_scan<<<dim3(64), dim3(256), 0, stream>>>(kn_all, norm_all, read_ws);
  p3a<<<dim3(64), dim3(128), 0, stream>>>(read_ws, rp_w, rp_b, o1_ws);
  p3b<<<dim3(125), dim3(256), 0, stream>>>(o1_ws, out_w, out_b, (float*)d_out);
}

// Round 5
// 2174.573 us; speedup vs baseline: 1.5156x; 1.0405x over previous
//
#include <hip/hip_runtime.h>
#include <hip/hip_bf16.h>

#define Bn 64
#define Ln 2048
#define Hn 128
#define Vn 32000
#define THn 256            // 2*H
#define LAMBDA_ (1.0f/2048.0f)
#define CC 32              // scan chunk size
#define NCH (Ln/CC)        // 64 chunks
#define KSTR 164           // kn_l row stride (floats): 8 groups of 16 pad 20
#define VSTR 132           // vpd row stride
#define GSTR 36            // Gt row stride

__device__ __forceinline__ float rdlane(float v, int s) {
  return __int_as_float(__builtin_amdgcn_readlane(__float_as_int(v), s));
}

// ---------------------------------------------------------------------------
// Phase 1: embed gather + FF1+FF2 (fused over o-quarters) + residual + LN +
// k-projection. 64 tokens per block, 4 waves. (unchanged from r4)
// ---------------------------------------------------------------------------
__global__ __launch_bounds__(256, 3) void p1_fused(
    const int* __restrict__ seq,
    const float* __restrict__ embed_w,
    const float* __restrict__ ff_w1, const float* __restrict__ ff_b1,
    const float* __restrict__ ff_w2, const float* __restrict__ ff_b2,
    const float* __restrict__ ln_g, const float* __restrict__ ln_b,
    const float* __restrict__ kp_w,
    float* __restrict__ kn_all, float* __restrict__ norm_all)
{
  __shared__ __align__(16) float h_l[128*64];   // [feature][token]
  __shared__ __align__(16) float u_q[64*64];    // one o-quarter of u, [o][token]
  __shared__ float part1[256], part2[256], rinv_l[64];
  __shared__ int sid[64];

  const int tid  = threadIdx.x;
  const int lane = tid & 63;                                  // token
  const int w    = __builtin_amdgcn_readfirstlane(tid >> 6);  // wave (uniform)
  const int tile0 = blockIdx.x * 64;

  if (tid < 64) sid[tid] = seq[tile0 + tid];
  __syncthreads();

  { // embed gather -> h_l[j][t]
    const int t = tid >> 2, part = tid & 3;
    const float4* erow =
        reinterpret_cast<const float4*>(embed_w + (size_t)sid[t]*Hn) + part*8;
    #pragma unroll
    for (int c = 0; c < 8; ++c) {
      float4 v = erow[c];
      int j = part*32 + c*4;
      h_l[(j+0)*64+t]=v.x; h_l[(j+1)*64+t]=v.y;
      h_l[(j+2)*64+t]=v.z; h_l[(j+3)*64+t]=v.w;
    }
  }
  __syncthreads();

  float x[32];
  #pragma unroll
  for (int ii=0;ii<32;++ii) x[ii]=0.f;

  // ---- FF1 + FF2, fused over 4 o-quarters of 64 ----
  #pragma unroll 1
  for (int p=0;p<4;++p) {
    float u[16];
    #pragma unroll
    for (int oi=0;oi<16;++oi) u[oi] = ff_b1[p*64 + w*16 + oi];
    #pragma unroll 1
    for (int kq=0;kq<4;++kq) {
      float hv[32];
      #pragma unroll
      for (int j=0;j<32;++j) hv[j] = h_l[(kq*32+j)*64 + lane];
      #pragma unroll
      for (int oi=0;oi<16;++oi) {
        const float4* w4 = reinterpret_cast<const float4*>(
            ff_w1 + (size_t)(p*64 + w*16 + oi)*Hn + kq*32);
        float a0=0,a1=0,a2=0,a3=0;
        #pragma unroll
        for (int q=0;q<8;++q) {
          float4 wv = w4[q];
          a0 += hv[q*4+0]*wv.x; a1 += hv[q*4+1]*wv.y;
          a2 += hv[q*4+2]*wv.z; a3 += hv[q*4+3]*wv.w;
        }
        u[oi] += (a0+a1)+(a2+a3);
      }
    }
    if (p) __syncthreads();          // prev pass FF2 done before u_q overwrite
    #pragma unroll
    for (int oi=0;oi<16;++oi) u_q[(w*16+oi)*64 + lane] = fmaxf(u[oi], 0.f);
    __syncthreads();
    #pragma unroll 1
    for (int og=0;og<2;++og) {
      float uv[32];
      #pragma unroll
      for (int j=0;j<32;++j) uv[j] = u_q[(og*32+j)*64 + lane];
      #pragma unroll
      for (int ii=0;ii<32;++ii) {
        const float4* w4 = reinterpret_cast<const float4*>(
            ff_w2 + (size_t)(w*32+ii)*THn + p*64 + og*32);
        float a0=0,a1=0,a2=0,a3=0;
        #pragma unroll
        for (int q=0;q<8;++q) {
          float4 wv = w4[q];
          a0 += uv[q*4+0]*wv.x; a1 += uv[q*4+1]*wv.y;
          a2 += uv[q*4+2]*wv.z; a3 += uv[q*4+3]*wv.w;
        }
        x[ii] += (a0+a1)+(a2+a3);
      }
    }
  }

  // ---- residual + LayerNorm ----
  const int i0 = w*32;
  float s1=0.f, s2=0.f;
  #pragma unroll
  for (int ii=0;ii<32;++ii) {
    x[ii] += ff_b2[i0+ii] + h_l[(i0+ii)*64 + lane];
    s1 += x[ii]; s2 += x[ii]*x[ii];
  }
  part1[w*64+lane]=s1; part2[w*64+lane]=s2;
  __syncthreads();
  float mu=0.f, ms=0.f;
  #pragma unroll
  for (int ww=0;ww<4;++ww) { mu += part1[ww*64+lane]; ms += part2[ww*64+lane]; }
  mu *= (1.0f/128.0f); ms *= (1.0f/128.0f);
  const float rstd = rsqrtf(ms - mu*mu + 1e-5f);
  #pragma unroll
  for (int ii=0;ii<32;++ii)
    h_l[(i0+ii)*64 + lane] = (x[ii]-mu)*rstd*ln_g[i0+ii] + ln_b[i0+ii];
  __syncthreads();

  // ---- k projection ----
  float kacc[32];
  #pragma unroll
  for (int oo=0;oo<32;++oo) kacc[oo]=0.f;
  #pragma unroll 1
  for (int ib=0;ib<4;++ib) {
    float hv[32];
    #pragma unroll
    for (int j=0;j<32;++j) hv[j] = h_l[(ib*32+j)*64 + lane];
    #pragma unroll
    for (int oo=0;oo<32;++oo) {
      const float4* w4 = reinterpret_cast<const float4*>(
          kp_w + (size_t)(i0+oo)*Hn + ib*32);
      float a0=0,a1=0,a2=0,a3=0;
      #pragma unroll
      for (int q=0;q<8;++q) {
        float4 wv = w4[q];
        a0 += hv[q*4+0]*wv.x; a1 += hv[q*4+1]*wv.y;
        a2 += hv[q*4+2]*wv.z; a3 += hv[q*4+3]*wv.w;
      }
      kacc[oo] += (a0+a1)+(a2+a3);
    }
  }
  float ps=0.f;
  #pragma unroll
  for (int oo=0;oo<32;++oo) ps += kacc[oo]*kacc[oo];
  part1[w*64+lane]=ps;
  __syncthreads();
  if (tid<64) {
    float nn = part1[tid]+part1[64+tid]+part1[128+tid]+part1[192+tid];
    float nrm = sqrtf(nn);
    norm_all[tile0+tid]=nrm;
    rinv_l[tid]=1.0f/fmaxf(nrm,1e-12f);
  }
  __syncthreads();
  const float riv = rinv_l[lane];
  float4* dst = reinterpret_cast<float4*>(kn_all + (size_t)(tile0+lane)*Hn + w*32);
  #pragma unroll
  for (int q=0;q<8;++q)
    dst[q] = make_float4(kacc[q*4]*riv, kacc[q*4+1]*riv,
                         kacc[q*4+2]*riv, kacc[q*4+3]*riv);
}

// ---------------------------------------------------------------------------
// Phase 2: chunked WY gated delta-rule scan, C=32. One block (512 thr) per
// batch. M in VGPRs: thread = 2 rows x 16 cols. Per chunk:
//   [Gram + A]  B1  [wave0: serial recurrence | waves1-4: stage next kn]  B2
//   [E: M += AD*Kn]  B3
// kn double-buffered; Gram remapped so row sets per read span all bank slots.
// ---------------------------------------------------------------------------
__global__ __launch_bounds__(512, 2) void p2_scan(
    const float* __restrict__ kn_all, const float* __restrict__ norm_all,
    float* __restrict__ read_ws)
{
  const int tid  = threadIdx.x;
  const int lane = tid & 63;
  const int wv   = tid >> 6;      // 0..7
  const int ib   = tid >> 3;      // 0..63 -> rows 2ib, 2ib+1
  const int cb   = tid & 7;       // cols 16cb..16cb+15
  const int b    = blockIdx.x;

  __shared__ __align__(16) float kn_l[2*CC*KSTR]; // double-buffered kn tiles
  __shared__ __align__(16) float vpd [CC*VSTR];   // vp0, then a_t*d_t
  __shared__ __align__(16) float Gt  [CC*GSTR];   // Gt[t][s] = kn_s . kn_t
  __shared__ float nrm_l[2*CC];

  float M[2][16];
  #pragma unroll
  for (int r=0;r<2;++r)
    #pragma unroll
    for (int c=0;c<16;++c) M[r][c]=0.f;

  const float* knb = kn_all + (size_t)b*Ln*Hn;
  const float* nb  = norm_all + (size_t)b*Ln;

  { // stage chunk 0 into buffer 0
    if (tid < 256) {
      const int t = tid>>3, ig = tid&7;
      const float4* src = reinterpret_cast<const float4*>(knb + t*Hn + ig*16);
      float* d0 = &kn_l[t*KSTR + ig*20];
      float4 v0=src[0], v1=src[1], v2=src[2], v3=src[3];
      *reinterpret_cast<float4*>(d0+0)=v0;  *reinterpret_cast<float4*>(d0+4)=v1;
      *reinterpret_cast<float4*>(d0+8)=v2;  *reinterpret_cast<float4*>(d0+12)=v3;
    }
    if (tid >= 256 && tid < 256+CC) nrm_l[tid-256] = nb[tid-256];
  }
  __syncthreads();

  #pragma unroll 1
  for (int ch=0; ch<NCH; ++ch) {
    const int cur = ch & 1;
    const float* knc = &kn_l[cur*CC*KSTR];
    const bool havenext = (ch+1 < NCH);

    // prefetch next chunk into regs (staging threads only)
    float4 pf0, pf1, pf2, pf3; float pfn = 0.f;
    if (havenext) {
      if (tid >= 64 && tid < 320) {
        const int idx = tid-64, t = idx>>3, ig = idx&7;
        const float4* src = reinterpret_cast<const float4*>(
            knb + (size_t)(ch+1)*CC*Hn + t*Hn + ig*16);
        pf0=src[0]; pf1=src[1]; pf2=src[2]; pf3=src[3];
      }
      if (tid >= 320 && tid < 320+CC) pfn = nb[(ch+1)*CC + (tid-320)];
    }

    { // ---- Gram: thread -> G[t][sp], G[t][sp+16]; conflict-light rows ----
      const int t = tid >> 4, sp = tid & 15;
      float g0=0.f, g1=0.f;
      #pragma unroll 4
      for (int k4=0;k4<32;++k4) {
        const int ka = (k4>>2)*20 + (k4&3)*4;
        float4 ft = *reinterpret_cast<const float4*>(&knc[t*KSTR+ka]);
        float4 fa = *reinterpret_cast<const float4*>(&knc[sp*KSTR+ka]);
        float4 fb = *reinterpret_cast<const float4*>(&knc[(sp+16)*KSTR+ka]);
        g0 += ft.x*fa.x+ft.y*fa.y+ft.z*fa.z+ft.w*fa.w;
        g1 += ft.x*fb.x+ft.y*fb.y+ft.z*fb.z+ft.w*fb.w;
      }
      Gt[t*GSTR + sp]      = g0;
      Gt[t*GSTR + sp + 16] = g1;
    }

    // ---- Phase A: vp0 = M * Kn^T ----
    #pragma unroll 1
    for (int tb=0;tb<2;++tb) {
      float acc[2][16];
      #pragma unroll
      for (int r=0;r<2;++r)
        #pragma unroll
        for (int tt=0;tt<16;++tt) acc[r][tt]=0.f;
      #pragma unroll
      for (int tt=0;tt<16;++tt) {
        const int t = tb*16+tt;
        float f[16];
        #pragma unroll
        for (int q=0;q<4;++q) {
          float4 v = *reinterpret_cast<const float4*>(&knc[t*KSTR + cb*20 + 4*q]);
          f[4*q]=v.x; f[4*q+1]=v.y; f[4*q+2]=v.z; f[4*q+3]=v.w;
        }
        #pragma unroll
        for (int c=0;c<16;++c) {
          acc[0][tt] += M[0][c]*f[c];
          acc[1][tt] += M[1][c]*f[c];
        }
      }
      #pragma unroll
      for (int r=0;r<2;++r)
        #pragma unroll
        for (int tt=0;tt<16;++tt) {
          float v = acc[r][tt];
          v += __shfl_xor(v,1); v += __shfl_xor(v,2); v += __shfl_xor(v,4);
          acc[r][tt]=v;
        }
      #pragma unroll
      for (int tt=0;tt<16;++tt) {
        if ((tt>>1)==cb) {           // owner lane-group writes rows 2ib,2ib+1
          const int t = tb*16+tt;
          *reinterpret_cast<float2*>(&vpd[t*VSTR + 2*ib]) =
              make_float2(acc[0][tt], acc[1][tt]);
        }
      }
    }
    __syncthreads();                       // B1: vpd(vp0) + Gt ready

    // ---- serial d-recurrence (wave 0) | staging (waves 1-4) ----
    if (wv==0) {
      float ad0[CC], ad1[CC], gr[CC];
      #pragma unroll
      for (int t=0;t<CC;++t) gr[t] = Gt[t*GSTR + (lane&31)];   // conflict-free
      const int sw0 = (lane>>4)*20 + (lane&15);
      #pragma unroll
      for (int t=0;t<CC;++t) {
        const float nrm = nrm_l[cur*CC + t];
        const float kn0 = knc[t*KSTR + sw0];        // comp lane
        const float kn1 = knc[t*KSTR + 80 + sw0];   // comp 64+lane
        float a0e = nrm*kn0 - vpd[t*VSTR + lane];
        float a1e = nrm*kn1 - vpd[t*VSTR + 64 + lane];
        float a0o = 0.f, a1o = 0.f;
        #pragma unroll
        for (int s=0; s<t; ++s) {                   // static: only s<t emitted
          const float g = rdlane(gr[t], s);         // uniform scalar (SGPR)
          if (s & 1) { a0o -= g*ad0[s]; a1o -= g*ad1[s]; }
          else       { a0e -= g*ad0[s]; a1e -= g*ad1[s]; }
        }
        const float acc0 = a0e + a0o;
        const float acc1 = a1e + a1o;
        float sq = acc0*acc0 + acc1*acc1;
        sq += __shfl_xor(sq,32); sq += __shfl_xor(sq,16); sq += __shfl_xor(sq,8);
        sq += __shfl_xor(sq,4);  sq += __shfl_xor(sq,2);  sq += __shfl_xor(sq,1);
        if (ch==NCH-1 && t==CC-1) {
          // query: read = M@q, q = nrm*kn; M.kn = nrm*kn - d
          read_ws[b*Hn + lane]      = nrm*(nrm*kn0 - acc0);
          read_ws[b*Hn + 64 + lane] = nrm*(nrm*kn1 - acc1);
        } else {
          const float at = (sqrtf(sq) >= 0.4f*nrm) ? LAMBDA_ : 0.f;
          ad0[t] = at*acc0; ad1[t] = at*acc1;
          vpd[t*VSTR + lane]      = ad0[t];          // publish a*d for E phase
          vpd[t*VSTR + 64 + lane] = ad1[t];
        }
      }
    } else if (havenext) {
      // stage prefetched chunk ch+1 into idle buffer (waves 1-4 + nrm thrds)
      if (tid >= 64 && tid < 320) {
        const int idx = tid-64, t = idx>>3, ig = idx&7;
        float* d0 = &kn_l[(1-cur)*CC*KSTR + t*KSTR + ig*20];
        *reinterpret_cast<float4*>(d0+0)=pf0;  *reinterpret_cast<float4*>(d0+4)=pf1;
        *reinterpret_cast<float4*>(d0+8)=pf2;  *reinterpret_cast<float4*>(d0+12)=pf3;
      }
      if (tid >= 320 && tid < 320+CC) nrm_l[(1-cur)*CC + (tid-320)] = pfn;
    }
    __syncthreads();                       // B2: ad + staged tile ready
    if (ch==NCH-1) break;

    // ---- Phase E: M += sum_s (a_s d_s) x kn_s (ad==0 when gate off) ----
    #pragma unroll 1
    for (int s=0;s<CC;++s) {
      float2 ad = *reinterpret_cast<const float2*>(&vpd[s*VSTR + 2*ib]);
      float f[16];
      #pragma unroll
      for (int q=0;q<4;++q) {
        float4 v = *reinterpret_cast<const float4*>(&knc[s*KSTR + cb*20 + 4*q]);
        f[4*q]=v.x; f[4*q+1]=v.y; f[4*q+2]=v.z; f[4*q+3]=v.w;
      }
      #pragma unroll
      for (int c=0;c<16;++c) {
        M[0][c] += ad.x*f[c];
        M[1][c] += ad.y*f[c];
      }
    }
    __syncthreads();                       // B3: vpd free for next A
  }
}

// ---------------------------------------------------------------------------
// Phase 3a: o1 = read @ rp_w^T + rp_b   (tiny)
// ---------------------------------------------------------------------------
__global__ __launch_bounds__(128) void p3a(
    const float* __restrict__ read_ws, const float* __restrict__ rp_w,
    const float* __restrict__ rp_b, float* __restrict__ o1_ws)
{
  __shared__ float rd[128];
  const int b = blockIdx.x, t = threadIdx.x;
  rd[t] = read_ws[b*Hn + t];
  __syncthreads();
  float acc = rp_b[t];
  const float* wr = rp_w + t*Hn;
  #pragma unroll 4
  for (int i = 0; i < Hn; ++i) acc += rd[i]*wr[i];
  o1_ws[b*Hn + t] = acc;
}

// ---------------------------------------------------------------------------
// Phase 3b: out = o1 @ out_w^T + out_b
// ---------------------------------------------------------------------------
__global__ __launch_bounds__(256) void p3b(
    const float* __restrict__ o1_ws, const float* __restrict__ out_w,
    const float* __restrict__ out_b, float* __restrict__ out)
{
  __shared__ __align__(16) float o1[8192];       // [64][128]
  const int tid = threadIdx.x;
  #pragma unroll
  for (int c = 0; c < 32; ++c) o1[c*256+tid] = o1_ws[c*256+tid];
  __syncthreads();
  const int v = blockIdx.x*256 + tid;            // 125*256 == 32000
  float acc[64];
  const float ob = out_b[v];
  #pragma unroll
  for (int bb = 0; bb < 64; ++bb) acc[bb] = ob;
  const float4* wrow = reinterpret_cast<const float4*>(out_w + (size_t)v*Hn);
  #pragma unroll 1
  for (int r4 = 0; r4 < 32; ++r4) {
    const float4 wv = wrow[r4];
    #pragma unroll
    for (int bb = 0; bb < 64; ++bb) {
      const float4 ov = *reinterpret_cast<const float4*>(&o1[bb*Hn + r4*4]);
      acc[bb] += wv.x*ov.x + wv.y*ov.y + wv.z*ov.z + wv.w*ov.w;
    }
  }
  #pragma unroll
  for (int bb = 0; bb < 64; ++bb) out[(size_t)bb*Vn + v] = acc[bb];
}

// ---------------------------------------------------------------------------
extern "C" void kernel_launch(void* const* d_in, const int* in_sizes, int n_in,
                              void* d_out, int out_size, void* d_ws, size_t ws_size,
                              hipStream_t stream)
{
  const int*   seq     = (const int*)  d_in[0];
  const float* embed_w = (const float*)d_in[1];
  const float* ff_w1   = (const float*)d_in[2];
  const float* ff_b1   = (const float*)d_in[3];
  const float* ff_w2   = (const float*)d_in[4];
  const float* ff_b2   = (const float*)d_in[5];
  const float* ln_g    = (const float*)d_in[6];
  const float* ln_b    = (const float*)d_in[7];
  const float* kp_w    = (const float*)d_in[8];
  const float* rp_w    = (const float*)d_in[9];
  const float* rp_b    = (const float*)d_in[10];
  const float* out_w   = (const float*)d_in[11];
  const float* out_b   = (const float*)d_in[12];

  float* ws       = (float*)d_ws;
  float* kn_all   = ws;                               // B*L*H
  float* norm_all = ws + (size_t)Bn*Ln*Hn;            // B*L
  float* read_ws  = norm_all + (size_t)Bn*Ln;         // B*H
  float* o1_ws    = read_ws + Bn*Hn;                  // B*H

  p1_fused<<<dim3(2048), dim3(256), 0, stream>>>(
      seq, embed_w, ff_w1, ff_b1, ff_w2, ff_b2, ln_g, ln_b, kp_w, kn_all, norm_all);
  p2_scan<<<dim3(64), dim3(512), 0, stream>>>(kn_all, norm_all, read_ws);
  p3a<<<dim3(64), dim3(128), 0, stream>>>(read_ws, rp_w, rp_b, o1_ws);
  p3b<<<dim3(125), dim3(256), 0, stream>>>(o1_ws, out_w, out_b, (float*)d_out);
}

// Round 6
// 1584.768 us; speedup vs baseline: 2.0796x; 1.3722x over previous
//
#include <hip/hip_runtime.h>
#include <hip/hip_bf16.h>

#define Bn 64
#define Ln 2048
#define Hn 128
#define Vn 32000
#define THn 256            // 2*H
#define LAMBDA_ (1.0f/2048.0f)
#define CC 32              // scan chunk size
#define NCH (Ln/CC)        // 64 chunks
#define KP  132            // kn_p row stride (uints), 16B-aligned rows
#define VS  132            // vpd row stride (floats)
#define GS  36             // Gt row stride
#define MSR 36             // m_scratch row stride (uints)
#define MSW 576            // m_scratch per-wave size (16*36)

typedef short bf16x8 __attribute__((ext_vector_type(8)));
typedef float f32x4  __attribute__((ext_vector_type(4)));

__device__ __forceinline__ float rdlane(float v, int s) {
  return __int_as_float(__builtin_amdgcn_readlane(__float_as_int(v), s));
}

// pack fp32 -> (bf16 hi in low16, bf16 lo in high16), truncation split
__device__ __forceinline__ uint32_t packhl(float x) {
  uint32_t bx = __float_as_uint(x);
  float hf = __uint_as_float(bx & 0xFFFF0000u);
  uint32_t bl = __float_as_uint(x - hf);
  return (bx >> 16) | (bl & 0xFFFF0000u);
}

struct FragHL { bf16x8 h; bf16x8 l; };
__device__ __forceinline__ FragHL mkfrag(const uint32_t* u) {
  union { uint32_t a[4]; bf16x8 v; } H, L;
  H.a[0] = __builtin_amdgcn_perm(u[1], u[0], 0x05040100u);
  H.a[1] = __builtin_amdgcn_perm(u[3], u[2], 0x05040100u);
  H.a[2] = __builtin_amdgcn_perm(u[5], u[4], 0x05040100u);
  H.a[3] = __builtin_amdgcn_perm(u[7], u[6], 0x05040100u);
  L.a[0] = __builtin_amdgcn_perm(u[1], u[0], 0x07060302u);
  L.a[1] = __builtin_amdgcn_perm(u[3], u[2], 0x07060302u);
  L.a[2] = __builtin_amdgcn_perm(u[5], u[4], 0x07060302u);
  L.a[3] = __builtin_amdgcn_perm(u[7], u[6], 0x07060302u);
  FragHL f; f.h = H.v; f.l = L.v; return f;
}

__device__ __forceinline__ void ld8(const uint32_t* p, uint32_t* u) {
  const uint4 a = *reinterpret_cast<const uint4*>(p);
  const uint4 b = *reinterpret_cast<const uint4*>(p + 4);
  u[0]=a.x; u[1]=a.y; u[2]=a.z; u[3]=a.w;
  u[4]=b.x; u[5]=b.y; u[6]=b.z; u[7]=b.w;
}

__device__ __forceinline__ f32x4 mfma16(bf16x8 a, bf16x8 b, f32x4 c) {
  return __builtin_amdgcn_mfma_f32_16x16x32_bf16(a, b, c, 0, 0, 0);
}

// ---------------------------------------------------------------------------
// Phase 1: embed gather + FF1+FF2 + residual + LN + k-projection.
// (unchanged from r5)
// ---------------------------------------------------------------------------
__global__ __launch_bounds__(256, 3) void p1_fused(
    const int* __restrict__ seq,
    const float* __restrict__ embed_w,
    const float* __restrict__ ff_w1, const float* __restrict__ ff_b1,
    const float* __restrict__ ff_w2, const float* __restrict__ ff_b2,
    const float* __restrict__ ln_g, const float* __restrict__ ln_b,
    const float* __restrict__ kp_w,
    float* __restrict__ kn_all, float* __restrict__ norm_all)
{
  __shared__ __align__(16) float h_l[128*64];   // [feature][token]
  __shared__ __align__(16) float u_q[64*64];    // one o-quarter of u, [o][token]
  __shared__ float part1[256], part2[256], rinv_l[64];
  __shared__ int sid[64];

  const int tid  = threadIdx.x;
  const int lane = tid & 63;                                  // token
  const int w    = __builtin_amdgcn_readfirstlane(tid >> 6);  // wave (uniform)
  const int tile0 = blockIdx.x * 64;

  if (tid < 64) sid[tid] = seq[tile0 + tid];
  __syncthreads();

  { // embed gather -> h_l[j][t]
    const int t = tid >> 2, part = tid & 3;
    const float4* erow =
        reinterpret_cast<const float4*>(embed_w + (size_t)sid[t]*Hn) + part*8;
    #pragma unroll
    for (int c = 0; c < 8; ++c) {
      float4 v = erow[c];
      int j = part*32 + c*4;
      h_l[(j+0)*64+t]=v.x; h_l[(j+1)*64+t]=v.y;
      h_l[(j+2)*64+t]=v.z; h_l[(j+3)*64+t]=v.w;
    }
  }
  __syncthreads();

  float x[32];
  #pragma unroll
  for (int ii=0;ii<32;++ii) x[ii]=0.f;

  // ---- FF1 + FF2, fused over 4 o-quarters of 64 ----
  #pragma unroll 1
  for (int p=0;p<4;++p) {
    float u[16];
    #pragma unroll
    for (int oi=0;oi<16;++oi) u[oi] = ff_b1[p*64 + w*16 + oi];
    #pragma unroll 1
    for (int kq=0;kq<4;++kq) {
      float hv[32];
      #pragma unroll
      for (int j=0;j<32;++j) hv[j] = h_l[(kq*32+j)*64 + lane];
      #pragma unroll
      for (int oi=0;oi<16;++oi) {
        const float4* w4 = reinterpret_cast<const float4*>(
            ff_w1 + (size_t)(p*64 + w*16 + oi)*Hn + kq*32);
        float a0=0,a1=0,a2=0,a3=0;
        #pragma unroll
        for (int q=0;q<8;++q) {
          float4 wv = w4[q];
          a0 += hv[q*4+0]*wv.x; a1 += hv[q*4+1]*wv.y;
          a2 += hv[q*4+2]*wv.z; a3 += hv[q*4+3]*wv.w;
        }
        u[oi] += (a0+a1)+(a2+a3);
      }
    }
    if (p) __syncthreads();
    #pragma unroll
    for (int oi=0;oi<16;++oi) u_q[(w*16+oi)*64 + lane] = fmaxf(u[oi], 0.f);
    __syncthreads();
    #pragma unroll 1
    for (int og=0;og<2;++og) {
      float uv[32];
      #pragma unroll
      for (int j=0;j<32;++j) uv[j] = u_q[(og*32+j)*64 + lane];
      #pragma unroll
      for (int ii=0;ii<32;++ii) {
        const float4* w4 = reinterpret_cast<const float4*>(
            ff_w2 + (size_t)(w*32+ii)*THn + p*64 + og*32);
        float a0=0,a1=0,a2=0,a3=0;
        #pragma unroll
        for (int q=0;q<8;++q) {
          float4 wv = w4[q];
          a0 += uv[q*4+0]*wv.x; a1 += uv[q*4+1]*wv.y;
          a2 += uv[q*4+2]*wv.z; a3 += uv[q*4+3]*wv.w;
        }
        x[ii] += (a0+a1)+(a2+a3);
      }
    }
  }

  // ---- residual + LayerNorm ----
  const int i0 = w*32;
  float s1=0.f, s2=0.f;
  #pragma unroll
  for (int ii=0;ii<32;++ii) {
    x[ii] += ff_b2[i0+ii] + h_l[(i0+ii)*64 + lane];
    s1 += x[ii]; s2 += x[ii]*x[ii];
  }
  part1[w*64+lane]=s1; part2[w*64+lane]=s2;
  __syncthreads();
  float mu=0.f, ms=0.f;
  #pragma unroll
  for (int ww=0;ww<4;++ww) { mu += part1[ww*64+lane]; ms += part2[ww*64+lane]; }
  mu *= (1.0f/128.0f); ms *= (1.0f/128.0f);
  const float rstd = rsqrtf(ms - mu*mu + 1e-5f);
  #pragma unroll
  for (int ii=0;ii<32;++ii)
    h_l[(i0+ii)*64 + lane] = (x[ii]-mu)*rstd*ln_g[i0+ii] + ln_b[i0+ii];
  __syncthreads();

  // ---- k projection ----
  float kacc[32];
  #pragma unroll
  for (int oo=0;oo<32;++oo) kacc[oo]=0.f;
  #pragma unroll 1
  for (int ib=0;ib<4;++ib) {
    float hv[32];
    #pragma unroll
    for (int j=0;j<32;++j) hv[j] = h_l[(ib*32+j)*64 + lane];
    #pragma unroll
    for (int oo=0;oo<32;++oo) {
      const float4* w4 = reinterpret_cast<const float4*>(
          kp_w + (size_t)(i0+oo)*Hn + ib*32);
      float a0=0,a1=0,a2=0,a3=0;
      #pragma unroll
      for (int q=0;q<8;++q) {
        float4 wv = w4[q];
        a0 += hv[q*4+0]*wv.x; a1 += hv[q*4+1]*wv.y;
        a2 += hv[q*4+2]*wv.z; a3 += hv[q*4+3]*wv.w;
      }
      kacc[oo] += (a0+a1)+(a2+a3);
    }
  }
  float ps=0.f;
  #pragma unroll
  for (int oo=0;oo<32;++oo) ps += kacc[oo]*kacc[oo];
  part1[w*64+lane]=ps;
  __syncthreads();
  if (tid<64) {
    float nn = part1[tid]+part1[64+tid]+part1[128+tid]+part1[192+tid];
    float nrm = sqrtf(nn);
    norm_all[tile0+tid]=nrm;
    rinv_l[tid]=1.0f/fmaxf(nrm,1e-12f);
  }
  __syncthreads();
  const float riv = rinv_l[lane];
  float4* dst = reinterpret_cast<float4*>(kn_all + (size_t)(tile0+lane)*Hn + w*32);
  #pragma unroll
  for (int q=0;q<8;++q)
    dst[q] = make_float4(kacc[q*4]*riv, kacc[q*4+1]*riv,
                         kacc[q*4+2]*riv, kacc[q*4+3]*riv);
}

// ---------------------------------------------------------------------------
// Phase 2: chunked WY gated delta-rule scan, C=32, MFMA edition.
// One block (512 thr = 8 waves) per batch. M rows 16w..16w+15 live in wave w
// as 8 f32x4 MFMA C/D accumulators. kn staged in LDS as packed bf16 hi/lo
// uints. Per chunk:
//   [Gram (waves 4-7, MFMA) + A: vp0=M*Kn^T (MFMA, per-wave panel spill)] B1
//   [wave0: serial fp32 d-recurrence] B2
//   [E: M += AD*Kn (MFMA)] B3  [stage next kn] B4
// ---------------------------------------------------------------------------
__global__ __launch_bounds__(512, 2) void p2_scan(
    const float* __restrict__ kn_all, const float* __restrict__ norm_all,
    float* __restrict__ read_ws)
{
  const int tid  = threadIdx.x;
  const int lane = tid & 63;
  const int wv   = __builtin_amdgcn_readfirstlane(tid >> 6);  // 0..7
  const int q    = lane >> 4;     // quad
  const int m    = lane & 15;
  const int b    = blockIdx.x;

  __shared__ __align__(16) uint32_t kn_p[CC*KP];  // packed bf16 hi/lo kn[t][c]
  __shared__ __align__(16) float    vpd [CC*VS];  // vp0, then a_t*d_t (fp32)
  __shared__ __align__(16) float    Gt  [CC*GS];  // G[t][s] = kn_t . kn_s
  __shared__ __align__(16) uint32_t msc [8*MSW];  // per-wave M panel scratch
  __shared__ float nrm_l[CC];

  f32x4 Macc[8];
  #pragma unroll
  for (int ct=0; ct<8; ++ct) Macc[ct] = (f32x4){0.f,0.f,0.f,0.f};

  const float* knb = kn_all + (size_t)b*Ln*Hn;
  const float* nb  = norm_all + (size_t)b*Ln;

  { // stage chunk 0: read fp32 kn, pack hi/lo, write kn_p
    if (tid < 256) {
      const int t = tid>>3, g = tid&7;
      const float4* src = reinterpret_cast<const float4*>(knb + t*Hn + g*16);
      uint32_t wbuf[16];
      #pragma unroll
      for (int i=0;i<4;++i) {
        float4 v = src[i];
        wbuf[4*i+0]=packhl(v.x); wbuf[4*i+1]=packhl(v.y);
        wbuf[4*i+2]=packhl(v.z); wbuf[4*i+3]=packhl(v.w);
      }
      uint4* dst = reinterpret_cast<uint4*>(&kn_p[t*KP + g*16]);
      dst[0]=make_uint4(wbuf[0],wbuf[1],wbuf[2],wbuf[3]);
      dst[1]=make_uint4(wbuf[4],wbuf[5],wbuf[6],wbuf[7]);
      dst[2]=make_uint4(wbuf[8],wbuf[9],wbuf[10],wbuf[11]);
      dst[3]=make_uint4(wbuf[12],wbuf[13],wbuf[14],wbuf[15]);
    }
    if (tid >= 256 && tid < 256+CC) nrm_l[tid-256] = nb[tid-256];
  }
  __syncthreads();

  #pragma unroll 1
  for (int ch=0; ch<NCH; ++ch) {
    const bool havenext = (ch+1 < NCH);
    // prefetch next chunk (fp32) into registers
    float4 pfa, pfb, pfc, pfd; float pfn = 0.f;
    if (havenext) {
      if (tid < 256) {
        const int t = tid>>3, g = tid&7;
        const float4* src = reinterpret_cast<const float4*>(
            knb + (size_t)(ch+1)*CC*Hn + t*Hn + g*16);
        pfa=src[0]; pfb=src[1]; pfc=src[2]; pfd=src[3];
      }
      if (tid >= 256 && tid < 256+CC) pfn = nb[(ch+1)*CC + (tid-256)];
    }

    // ---- Gram via MFMA on waves 4-7: tile (ti,si) each ----
    if (wv >= 4) {
      const int ti = (wv-4)>>1, si = (wv-4)&1;
      f32x4 g = (f32x4){0.f,0.f,0.f,0.f};
      #pragma unroll
      for (int kk=0; kk<4; ++kk) {
        uint32_t ua[8], ub[8];
        ld8(&kn_p[(16*ti+m)*KP + 32*kk + 8*q], ua);
        ld8(&kn_p[(16*si+m)*KP + 32*kk + 8*q], ub);
        FragHL fa = mkfrag(ua), fb = mkfrag(ub);
        g = mfma16(fa.h, fb.h, g);
        g = mfma16(fa.h, fb.l, g);
        g = mfma16(fa.l, fb.h, g);
      }
      #pragma unroll
      for (int reg=0; reg<4; ++reg)
        Gt[(16*ti + 4*q + reg)*GS + 16*si + m] = g[reg];
    }

    // ---- Phase A: vp0 = M * Kn^T (all waves; rows 16wv..16wv+15) ----
    {
      f32x4 v0 = (f32x4){0.f,0.f,0.f,0.f};
      f32x4 v1 = (f32x4){0.f,0.f,0.f,0.f};
      uint32_t* mybase = &msc[wv*MSW];
      #pragma unroll
      for (int kk=0; kk<4; ++kk) {
        // spill M panel kk (cols 32kk..32kk+31) as packed hi/lo
        #pragma unroll
        for (int c2=0; c2<2; ++c2) {
          const int ct = 2*kk + c2;
          #pragma unroll
          for (int reg=0; reg<4; ++reg)
            mybase[(4*q+reg)*MSR + 16*c2 + m] = packhl(Macc[ct][reg]);
        }
        uint32_t ua[8], ub[8];
        ld8(&mybase[m*MSR + 8*q], ua);      // A-frag: M[m][32kk+8q+j]
        FragHL fa = mkfrag(ua);
        ld8(&kn_p[m*KP + 32*kk + 8*q], ub); // B-frag nt=0: kn[t=m][c]
        FragHL fb = mkfrag(ub);
        v0 = mfma16(fa.h, fb.h, v0);
        v0 = mfma16(fa.h, fb.l, v0);
        v0 = mfma16(fa.l, fb.h, v0);
        ld8(&kn_p[(16+m)*KP + 32*kk + 8*q], ub); // nt=1: t=16+m
        fb = mkfrag(ub);
        v1 = mfma16(fa.h, fb.h, v1);
        v1 = mfma16(fa.h, fb.l, v1);
        v1 = mfma16(fa.l, fb.h, v1);
      }
      // write vp0: rows 16wv+4q..+3 (contiguous), t = m / 16+m
      *reinterpret_cast<f32x4*>(&vpd[m*VS + 16*wv + 4*q]) = v0;
      *reinterpret_cast<f32x4*>(&vpd[(16+m)*VS + 16*wv + 4*q]) = v1;
    }
    __syncthreads();                       // B1: vpd(vp0) + Gt ready

    // ---- serial d-recurrence (wave 0, fp32, register-resident) ----
    if (wv==0) {
      float ad0[CC], ad1[CC], gr[CC];
      #pragma unroll
      for (int t=0;t<CC;++t) gr[t] = Gt[t*GS + (lane&31)];
      #pragma unroll
      for (int t=0;t<CC;++t) {
        const float nrm = nrm_l[t];
        const uint32_t u0 = kn_p[t*KP + lane];
        const uint32_t u1 = kn_p[t*KP + 64 + lane];
        const float kn0 = __uint_as_float(u0<<16) + __uint_as_float(u0 & 0xFFFF0000u);
        const float kn1 = __uint_as_float(u1<<16) + __uint_as_float(u1 & 0xFFFF0000u);
        float a0e = nrm*kn0 - vpd[t*VS + lane];
        float a1e = nrm*kn1 - vpd[t*VS + 64 + lane];
        float a0o = 0.f, a1o = 0.f;
        #pragma unroll
        for (int s=0; s<t; ++s) {                   // static: only s<t emitted
          const float g = rdlane(gr[t], s);         // uniform scalar (SGPR)
          if (s & 1) { a0o -= g*ad0[s]; a1o -= g*ad1[s]; }
          else       { a0e -= g*ad0[s]; a1e -= g*ad1[s]; }
        }
        const float acc0 = a0e + a0o;
        const float acc1 = a1e + a1o;
        float sq = acc0*acc0 + acc1*acc1;
        sq += __shfl_xor(sq,32); sq += __shfl_xor(sq,16); sq += __shfl_xor(sq,8);
        sq += __shfl_xor(sq,4);  sq += __shfl_xor(sq,2);  sq += __shfl_xor(sq,1);
        if (ch==NCH-1 && t==CC-1) {
          // query: read = M@q, q = nrm*kn; M.kn = nrm*kn - d
          read_ws[b*Hn + lane]      = nrm*(nrm*kn0 - acc0);
          read_ws[b*Hn + 64 + lane] = nrm*(nrm*kn1 - acc1);
        } else {
          const float at = (sqrtf(sq) >= 0.4f*nrm) ? LAMBDA_ : 0.f;
          ad0[t] = at*acc0; ad1[t] = at*acc1;
          vpd[t*VS + lane]      = ad0[t];            // publish a*d for E phase
          vpd[t*VS + 64 + lane] = ad1[t];
        }
      }
    }
    __syncthreads();                       // B2: ad ready
    if (ch==NCH-1) break;

    // ---- Phase E: M += AD^T * Kn via MFMA (all waves) ----
    {
      // A-frag: ad[t=8q+j][row=16wv+m], convert fp32 -> packed hi/lo
      uint32_t ap[8];
      #pragma unroll
      for (int j=0;j<8;++j)
        ap[j] = packhl(vpd[(8*q+j)*VS + 16*wv + m]);
      FragHL fa = mkfrag(ap);
      #pragma unroll
      for (int ct=0; ct<8; ++ct) {
        uint32_t bu[8];
        #pragma unroll
        for (int j=0;j<8;++j)
          bu[j] = kn_p[(8*q+j)*KP + 16*ct + m];
        FragHL fb = mkfrag(bu);
        Macc[ct] = mfma16(fa.h, fb.h, Macc[ct]);
        Macc[ct] = mfma16(fa.h, fb.l, Macc[ct]);
        Macc[ct] = mfma16(fa.l, fb.h, Macc[ct]);
      }
    }
    __syncthreads();                       // B3: kn_p free to overwrite

    // ---- stage prefetched chunk ch+1 ----
    if (tid < 256) {
      const int t = tid>>3, g = tid&7;
      uint32_t wbuf[16];
      wbuf[0]=packhl(pfa.x); wbuf[1]=packhl(pfa.y); wbuf[2]=packhl(pfa.z); wbuf[3]=packhl(pfa.w);
      wbuf[4]=packhl(pfb.x); wbuf[5]=packhl(pfb.y); wbuf[6]=packhl(pfb.z); wbuf[7]=packhl(pfb.w);
      wbuf[8]=packhl(pfc.x); wbuf[9]=packhl(pfc.y); wbuf[10]=packhl(pfc.z); wbuf[11]=packhl(pfc.w);
      wbuf[12]=packhl(pfd.x); wbuf[13]=packhl(pfd.y); wbuf[14]=packhl(pfd.z); wbuf[15]=packhl(pfd.w);
      uint4* dst = reinterpret_cast<uint4*>(&kn_p[t*KP + g*16]);
      dst[0]=make_uint4(wbuf[0],wbuf[1],wbuf[2],wbuf[3]);
      dst[1]=make_uint4(wbuf[4],wbuf[5],wbuf[6],wbuf[7]);
      dst[2]=make_uint4(wbuf[8],wbuf[9],wbuf[10],wbuf[11]);
      dst[3]=make_uint4(wbuf[12],wbuf[13],wbuf[14],wbuf[15]);
    }
    if (tid >= 256 && tid < 256+CC) nrm_l[tid-256] = pfn;
    __syncthreads();                       // B4: kn_p ready for next chunk
  }
}

// ---------------------------------------------------------------------------
// Phase 3a: o1 = read @ rp_w^T + rp_b   (tiny)
// ---------------------------------------------------------------------------
__global__ __launch_bounds__(128) void p3a(
    const float* __restrict__ read_ws, const float* __restrict__ rp_w,
    const float* __restrict__ rp_b, float* __restrict__ o1_ws)
{
  __shared__ float rd[128];
  const int b = blockIdx.x, t = threadIdx.x;
  rd[t] = read_ws[b*Hn + t];
  __syncthreads();
  float acc = rp_b[t];
  const float* wr = rp_w + t*Hn;
  #pragma unroll 4
  for (int i = 0; i < Hn; ++i) acc += rd[i]*wr[i];
  o1_ws[b*Hn + t] = acc;
}

// ---------------------------------------------------------------------------
// Phase 3b: out = o1 @ out_w^T + out_b
// ---------------------------------------------------------------------------
__global__ __launch_bounds__(256) void p3b(
    const float* __restrict__ o1_ws, const float* __restrict__ out_w,
    const float* __restrict__ out_b, float* __restrict__ out)
{
  __shared__ __align__(16) float o1[8192];       // [64][128]
  const int tid = threadIdx.x;
  #pragma unroll
  for (int c = 0; c < 32; ++c) o1[c*256+tid] = o1_ws[c*256+tid];
  __syncthreads();
  const int v = blockIdx.x*256 + tid;            // 125*256 == 32000
  float acc[64];
  const float ob = out_b[v];
  #pragma unroll
  for (int bb = 0; bb < 64; ++bb) acc[bb] = ob;
  const float4* wrow = reinterpret_cast<const float4*>(out_w + (size_t)v*Hn);
  #pragma unroll 1
  for (int r4 = 0; r4 < 32; ++r4) {
    const float4 wv = wrow[r4];
    #pragma unroll
    for (int bb = 0; bb < 64; ++bb) {
      const float4 ov = *reinterpret_cast<const float4*>(&o1[bb*Hn + r4*4]);
      acc[bb] += wv.x*ov.x + wv.y*ov.y + wv.z*ov.z + wv.w*ov.w;
    }
  }
  #pragma unroll
  for (int bb = 0; bb < 64; ++bb) out[(size_t)bb*Vn + v] = acc[bb];
}

// ---------------------------------------------------------------------------
extern "C" void kernel_launch(void* const* d_in, const int* in_sizes, int n_in,
                              void* d_out, int out_size, void* d_ws, size_t ws_size,
                              hipStream_t stream)
{
  const int*   seq     = (const int*)  d_in[0];
  const float* embed_w = (const float*)d_in[1];
  const float* ff_w1   = (const float*)d_in[2];
  const float* ff_b1   = (const float*)d_in[3];
  const float* ff_w2   = (const float*)d_in[4];
  const float* ff_b2   = (const float*)d_in[5];
  const float* ln_g    = (const float*)d_in[6];
  const float* ln_b    = (const float*)d_in[7];
  const float* kp_w    = (const float*)d_in[8];
  const float* rp_w    = (const float*)d_in[9];
  const float* rp_b    = (const float*)d_in[10];
  const float* out_w   = (const float*)d_in[11];
  const float* out_b   = (const float*)d_in[12];

  float* ws       = (float*)d_ws;
  float* kn_all   = ws;                               // B*L*H
  float* norm_all = ws + (size_t)Bn*Ln*Hn;            // B*L
  float* read_ws  = norm_all + (size_t)Bn*Ln;         // B*H
  float* o1_ws    = read_ws + Bn*Hn;                  // B*H

  p1_fused<<<dim3(2048), dim3(256), 0, stream>>>(
      seq, embed_w, ff_w1, ff_b1, ff_w2, ff_b2, ln_g, ln_b, kp_w, kn_all, norm_all);
  p2_scan<<<dim3(64), dim3(512), 0, stream>>>(kn_all, norm_all, read_ws);
  p3a<<<dim3(64), dim3(128), 0, stream>>>(read_ws, rp_w, rp_b, o1_ws);
  p3b<<<dim3(125), dim3(256), 0, stream>>>(o1_ws, out_w, out_b, (float*)d_out);
}

// Round 7
// 1073.199 us; speedup vs baseline: 3.0710x; 1.4767x over previous
//
#include <hip/hip_runtime.h>
#include <hip/hip_bf16.h>
#include <stdint.h>

#define Bn 64
#define Ln 2048
#define Hn 128
#define Vn 32000
#define THn 256            // 2*H
#define LAMBDA_ (1.0f/2048.0f)
#define CC 32              // scan chunk size
#define NCH (Ln/CC)        // 64 chunks
#define KP  132            // p2 kn_p row stride (uints)
#define VS  132            // p2 vpd row stride (floats)
#define GS  36             // p2 Gt row stride
#define MSR 36             // p2 m_scratch row stride (uints)
#define MSW 576            // p2 m_scratch per-wave size (16*36)
#define HS  132            // p1 h_p/u_p row stride (uints)

typedef short bf16x8 __attribute__((ext_vector_type(8)));
typedef float f32x4  __attribute__((ext_vector_type(4)));

__device__ __forceinline__ float rdlane(float v, int s) {
  return __int_as_float(__builtin_amdgcn_readlane(__float_as_int(v), s));
}

// pack fp32 -> (bf16 hi in low16, bf16 lo in high16), truncation split
__device__ __forceinline__ uint32_t packhl(float x) {
  uint32_t bx = __float_as_uint(x);
  float hf = __uint_as_float(bx & 0xFFFF0000u);
  uint32_t bl = __float_as_uint(x - hf);
  return (bx >> 16) | (bl & 0xFFFF0000u);
}
__device__ __forceinline__ float unpackhl(uint32_t u) {
  return __uint_as_float(u << 16) + __uint_as_float(u & 0xFFFF0000u);
}

struct FragHL { bf16x8 h; bf16x8 l; };
__device__ __forceinline__ FragHL mkfrag(const uint32_t* u) {
  union { uint32_t a[4]; bf16x8 v; } H, L;
  H.a[0] = __builtin_amdgcn_perm(u[1], u[0], 0x05040100u);
  H.a[1] = __builtin_amdgcn_perm(u[3], u[2], 0x05040100u);
  H.a[2] = __builtin_amdgcn_perm(u[5], u[4], 0x05040100u);
  H.a[3] = __builtin_amdgcn_perm(u[7], u[6], 0x05040100u);
  L.a[0] = __builtin_amdgcn_perm(u[1], u[0], 0x07060302u);
  L.a[1] = __builtin_amdgcn_perm(u[3], u[2], 0x07060302u);
  L.a[2] = __builtin_amdgcn_perm(u[5], u[4], 0x07060302u);
  L.a[3] = __builtin_amdgcn_perm(u[7], u[6], 0x07060302u);
  FragHL f; f.h = H.v; f.l = L.v; return f;
}

__device__ __forceinline__ void ld8(const uint32_t* p, uint32_t* u) {
  const uint4 a = *reinterpret_cast<const uint4*>(p);
  const uint4 b = *reinterpret_cast<const uint4*>(p + 4);
  u[0]=a.x; u[1]=a.y; u[2]=a.z; u[3]=a.w;
  u[4]=b.x; u[5]=b.y; u[6]=b.z; u[7]=b.w;
}

__device__ __forceinline__ bf16x8 asbf(uint4 u) {
  union { uint4 a; bf16x8 v; } c; c.a = u; return c.v;
}

__device__ __forceinline__ f32x4 mfma16(bf16x8 a, bf16x8 b, f32x4 c) {
  return __builtin_amdgcn_mfma_f32_16x16x32_bf16(a, b, c, 0, 0, 0);
}

// ---------------------------------------------------------------------------
// p0: pack weights once into fragment-ready hi/lo bf16-pair arrays in ws.
// wp layout: [w1h 16384][w1l 16384][w2h 16384][w2l 16384][kph 8192][kpl 8192]
// word j of row r = bf16(x_{2j}) | bf16(x_{2j+1})<<16.
// ---------------------------------------------------------------------------
__global__ __launch_bounds__(256) void p0_pack(
    const float* __restrict__ w1, const float* __restrict__ w2,
    const float* __restrict__ kp, uint32_t* __restrict__ wp)
{
  const int id = blockIdx.x*256 + threadIdx.x;   // pair index, 0..40959
  const float* src; uint32_t *dh, *dl; int p;
  if (id < 16384)      { src = w1; p = id;         dh = wp;         dl = wp+16384; }
  else if (id < 32768) { src = w2; p = id-16384;   dh = wp+32768;   dl = wp+49152; }
  else                 { src = kp; p = id-32768;   dh = wp+65536;   dl = wp+73728; }
  const float x0 = src[2*p], x1 = src[2*p+1];
  const uint32_t b0 = __float_as_uint(x0), b1 = __float_as_uint(x1);
  const float l0f = x0 - __uint_as_float(b0 & 0xFFFF0000u);
  const float l1f = x1 - __uint_as_float(b1 & 0xFFFF0000u);
  dh[p] = (b0 >> 16) | ((b1 >> 16) << 16);
  dl[p] = (__float_as_uint(l0f) >> 16) | ((__float_as_uint(l1f) >> 16) << 16);
}

// ---------------------------------------------------------------------------
// Phase 1 (MFMA edition): embed gather + FF1+FF2 (two 128-col halves) +
// residual + LN + k-projection. 64 tokens/block, 4 waves = column panels.
// A-operands (h, u, hn) packed hi/lo in LDS; B-operands (weights) read as
// fragment-ready uint4 from global (L1-resident). kn written packed hi/lo.
// ---------------------------------------------------------------------------
__global__ __launch_bounds__(256, 2) void p1_fused(
    const int* __restrict__ seq,
    const float* __restrict__ embed_w,
    const uint32_t* __restrict__ wp,
    const float* __restrict__ ff_b1, const float* __restrict__ ff_b2,
    const float* __restrict__ ln_g, const float* __restrict__ ln_b,
    uint32_t* __restrict__ knp_all, float* __restrict__ norm_all)
{
  __shared__ __align__(16) uint32_t h_p[64*HS];   // packed h, later packed hn
  __shared__ __align__(16) uint32_t u_p[64*HS];   // packed u (one 128-col half)
  __shared__ float part1[256], part2[256];
  __shared__ float mul[64], rsl[64];
  __shared__ int sid[64];

  const int tid  = threadIdx.x;
  const int lane = tid & 63;
  const int w    = __builtin_amdgcn_readfirstlane(tid >> 6);  // wave (uniform)
  const int q4   = lane >> 4;     // quad
  const int m16  = lane & 15;
  const int tile0 = blockIdx.x * 64;

  const uint32_t* w1h = wp;
  const uint32_t* w1l = wp + 16384;
  const uint32_t* w2h = wp + 32768;
  const uint32_t* w2l = wp + 49152;
  const uint32_t* kph = wp + 65536;
  const uint32_t* kpl = wp + 73728;

  if (tid < 64) sid[tid] = seq[tile0 + tid];
  __syncthreads();

  { // embed gather -> packed h_p[token][feature]
    const int t = tid >> 2, part = tid & 3;
    const float4* erow =
        reinterpret_cast<const float4*>(embed_w + (size_t)sid[t]*Hn) + part*8;
    #pragma unroll
    for (int c = 0; c < 8; ++c) {
      float4 v = erow[c];
      int j = part*32 + c*4;
      h_p[t*HS+j+0] = packhl(v.x); h_p[t*HS+j+1] = packhl(v.y);
      h_p[t*HS+j+2] = packhl(v.z); h_p[t*HS+j+3] = packhl(v.w);
    }
  }
  __syncthreads();

  f32x4 acc2[4][2];
  #pragma unroll
  for (int tt=0;tt<4;++tt)
    #pragma unroll
    for (int ct=0;ct<2;++ct) acc2[tt][ct] = (f32x4){0.f,0.f,0.f,0.f};

  #pragma unroll 1
  for (int ho=0; ho<2; ++ho) {
    // ---- FF1 half: u[tok][128ho+32w+16ct+n] ----
    #pragma unroll 1
    for (int tt=0; tt<4; ++tt) {
      FragHL fa[4];
      #pragma unroll
      for (int kk=0;kk<4;++kk) {
        uint32_t ua[8];
        ld8(&h_p[(16*tt+m16)*HS + 32*kk + 8*q4], ua);
        fa[kk] = mkfrag(ua);
      }
      #pragma unroll
      for (int ct=0; ct<2; ++ct) {
        const int ob = 128*ho + 32*w + 16*ct;
        f32x4 a = (f32x4){0.f,0.f,0.f,0.f};
        #pragma unroll
        for (int kk=0;kk<4;++kk) {
          const size_t wi = (size_t)(ob+m16)*64 + 16*kk + 4*q4;
          bf16x8 bh = asbf(*reinterpret_cast<const uint4*>(&w1h[wi]));
          bf16x8 bl = asbf(*reinterpret_cast<const uint4*>(&w1l[wi]));
          a = mfma16(fa[kk].h, bh, a);
          a = mfma16(fa[kk].h, bl, a);
          a = mfma16(fa[kk].l, bh, a);
        }
        const float bb = ff_b1[ob + m16];
        #pragma unroll
        for (int reg=0;reg<4;++reg) {
          float uv = fmaxf(a[reg] + bb, 0.f);
          u_p[(16*tt+4*q4+reg)*HS + 32*w + 16*ct + m16] = packhl(uv);
        }
      }
    }
    __syncthreads();      // u half complete
    // ---- FF2 half: acc2 += u_half @ w2[:, 128ho..] ----
    #pragma unroll 1
    for (int tt=0; tt<4; ++tt) {
      FragHL fu[4];
      #pragma unroll
      for (int kk=0;kk<4;++kk) {
        uint32_t ua[8];
        ld8(&u_p[(16*tt+m16)*HS + 32*kk + 8*q4], ua);
        fu[kk] = mkfrag(ua);
      }
      #pragma unroll
      for (int ct=0; ct<2; ++ct) {
        const int ib = 32*w + 16*ct;
        f32x4 a = acc2[tt][ct];
        #pragma unroll
        for (int kk=0;kk<4;++kk) {
          const size_t wi = (size_t)(ib+m16)*128 + 64*ho + 16*kk + 4*q4;
          bf16x8 bh = asbf(*reinterpret_cast<const uint4*>(&w2h[wi]));
          bf16x8 bl = asbf(*reinterpret_cast<const uint4*>(&w2l[wi]));
          a = mfma16(fu[kk].h, bh, a);
          a = mfma16(fu[kk].h, bl, a);
          a = mfma16(fu[kk].l, bh, a);
        }
        acc2[tt][ct] = a;
      }
    }
    __syncthreads();      // FF2 reads done before next half overwrites u_p
  }

  // ---- bias + residual; LN partials ----
  float xx[4][2][4];
  #pragma unroll
  for (int tt=0;tt<4;++tt)
    #pragma unroll
    for (int ct=0;ct<2;++ct) {
      const int col = 32*w + 16*ct + m16;
      const float b2 = ff_b2[col];
      #pragma unroll
      for (int reg=0;reg<4;++reg) {
        const float hval = unpackhl(h_p[(16*tt+4*q4+reg)*HS + col]);
        xx[tt][ct][reg] = acc2[tt][ct][reg] + b2 + hval;
      }
    }
  #pragma unroll
  for (int tt=0;tt<4;++tt)
    #pragma unroll
    for (int reg=0;reg<4;++reg) {
      float s1 = xx[tt][0][reg] + xx[tt][1][reg];
      float s2 = xx[tt][0][reg]*xx[tt][0][reg] + xx[tt][1][reg]*xx[tt][1][reg];
      s1 += __shfl_xor(s1,1); s1 += __shfl_xor(s1,2);
      s1 += __shfl_xor(s1,4); s1 += __shfl_xor(s1,8);
      s2 += __shfl_xor(s2,1); s2 += __shfl_xor(s2,2);
      s2 += __shfl_xor(s2,4); s2 += __shfl_xor(s2,8);
      if (m16==0) {
        part1[w*64 + 16*tt+4*q4+reg] = s1;
        part2[w*64 + 16*tt+4*q4+reg] = s2;
      }
    }
  __syncthreads();
  if (tid < 64) {
    const float mu = (part1[tid]+part1[64+tid]+part1[128+tid]+part1[192+tid])*(1.0f/128.0f);
    const float ms = (part2[tid]+part2[64+tid]+part2[128+tid]+part2[192+tid])*(1.0f/128.0f);
    mul[tid] = mu;
    rsl[tid] = rsqrtf(ms - mu*mu + 1e-5f);
  }
  __syncthreads();

  // ---- hn = LN(x): overwrite h_p (wave-private cols) ----
  #pragma unroll
  for (int tt=0;tt<4;++tt)
    #pragma unroll
    for (int ct=0;ct<2;++ct) {
      const int col = 32*w + 16*ct + m16;
      const float g = ln_g[col], bb = ln_b[col];
      #pragma unroll
      for (int reg=0;reg<4;++reg) {
        const int tok = 16*tt+4*q4+reg;
        const float hn = (xx[tt][ct][reg] - mul[tok])*rsl[tok]*g + bb;
        h_p[tok*HS + col] = packhl(hn);
      }
    }
  __syncthreads();

  // ---- k projection ----
  f32x4 ak[4][2];
  #pragma unroll 1
  for (int tt=0;tt<4;++tt) {
    FragHL fh[4];
    #pragma unroll
    for (int kk=0;kk<4;++kk) {
      uint32_t ua[8];
      ld8(&h_p[(16*tt+m16)*HS + 32*kk + 8*q4], ua);
      fh[kk] = mkfrag(ua);
    }
    #pragma unroll
    for (int ct=0;ct<2;++ct) {
      const int ob = 32*w + 16*ct;
      f32x4 a = (f32x4){0.f,0.f,0.f,0.f};
      #pragma unroll
      for (int kk=0;kk<4;++kk) {
        const size_t wi = (size_t)(ob+m16)*64 + 16*kk + 4*q4;
        bf16x8 bh = asbf(*reinterpret_cast<const uint4*>(&kph[wi]));
        bf16x8 bl = asbf(*reinterpret_cast<const uint4*>(&kpl[wi]));
        a = mfma16(fh[kk].h, bh, a);
        a = mfma16(fh[kk].h, bl, a);
        a = mfma16(fh[kk].l, bh, a);
      }
      ak[tt][ct] = a;
    }
  }
  // ---- ||k|| ----
  #pragma unroll
  for (int tt=0;tt<4;++tt)
    #pragma unroll
    for (int reg=0;reg<4;++reg) {
      float s = ak[tt][0][reg]*ak[tt][0][reg] + ak[tt][1][reg]*ak[tt][1][reg];
      s += __shfl_xor(s,1); s += __shfl_xor(s,2);
      s += __shfl_xor(s,4); s += __shfl_xor(s,8);
      if (m16==0) part1[w*64 + 16*tt+4*q4+reg] = s;
    }
  __syncthreads();
  if (tid < 64) {
    const float nn = part1[tid]+part1[64+tid]+part1[128+tid]+part1[192+tid];
    const float nrm = sqrtf(nn);
    norm_all[tile0 + tid] = nrm;
    mul[tid] = 1.0f / fmaxf(nrm, 1e-12f);     // reuse mul as rinv
  }
  __syncthreads();
  // ---- kn = k*rinv, packed hi/lo, to global ----
  #pragma unroll
  for (int tt=0;tt<4;++tt)
    #pragma unroll
    for (int ct=0;ct<2;++ct) {
      const int col = 32*w + 16*ct + m16;
      #pragma unroll
      for (int reg=0;reg<4;++reg) {
        const int tok = 16*tt+4*q4+reg;
        knp_all[(size_t)(tile0+tok)*Hn + col] = packhl(ak[tt][ct][reg]*mul[tok]);
      }
    }
}

// ---------------------------------------------------------------------------
// Phase 2: chunked WY gated delta-rule scan, C=32, MFMA (r6, unchanged except
// kn arrives pre-packed -> staging is a raw copy).
// ---------------------------------------------------------------------------
__global__ __launch_bounds__(512, 2) void p2_scan(
    const uint32_t* __restrict__ knp_all, const float* __restrict__ norm_all,
    float* __restrict__ read_ws)
{
  const int tid  = threadIdx.x;
  const int lane = tid & 63;
  const int wv   = __builtin_amdgcn_readfirstlane(tid >> 6);  // 0..7
  const int q    = lane >> 4;     // quad
  const int m    = lane & 15;
  const int b    = blockIdx.x;

  __shared__ __align__(16) uint32_t kn_p[CC*KP];  // packed bf16 hi/lo kn[t][c]
  __shared__ __align__(16) float    vpd [CC*VS];  // vp0, then a_t*d_t (fp32)
  __shared__ __align__(16) float    Gt  [CC*GS];  // G[t][s] = kn_t . kn_s
  __shared__ __align__(16) uint32_t msc [8*MSW];  // per-wave M panel scratch
  __shared__ float nrm_l[CC];

  f32x4 Macc[8];
  #pragma unroll
  for (int ct=0; ct<8; ++ct) Macc[ct] = (f32x4){0.f,0.f,0.f,0.f};

  const uint32_t* knb = knp_all + (size_t)b*Ln*Hn;
  const float*    nb  = norm_all + (size_t)b*Ln;

  { // stage chunk 0 (raw copy, already packed)
    if (tid < 256) {
      const int t = tid>>3, g = tid&7;
      const uint4* src = reinterpret_cast<const uint4*>(knb + t*Hn + g*16);
      uint4* dst = reinterpret_cast<uint4*>(&kn_p[t*KP + g*16]);
      dst[0]=src[0]; dst[1]=src[1]; dst[2]=src[2]; dst[3]=src[3];
    }
    if (tid >= 256 && tid < 256+CC) nrm_l[tid-256] = nb[tid-256];
  }
  __syncthreads();

  #pragma unroll 1
  for (int ch=0; ch<NCH; ++ch) {
    const bool havenext = (ch+1 < NCH);
    uint4 pfa, pfb, pfc, pfd; float pfn = 0.f;
    if (havenext) {
      if (tid < 256) {
        const int t = tid>>3, g = tid&7;
        const uint4* src = reinterpret_cast<const uint4*>(
            knb + (size_t)(ch+1)*CC*Hn + t*Hn + g*16);
        pfa=src[0]; pfb=src[1]; pfc=src[2]; pfd=src[3];
      }
      if (tid >= 256 && tid < 256+CC) pfn = nb[(ch+1)*CC + (tid-256)];
    }

    // ---- Gram via MFMA on waves 4-7 ----
    if (wv >= 4) {
      const int ti = (wv-4)>>1, si = (wv-4)&1;
      f32x4 g = (f32x4){0.f,0.f,0.f,0.f};
      #pragma unroll
      for (int kk=0; kk<4; ++kk) {
        uint32_t ua[8], ub[8];
        ld8(&kn_p[(16*ti+m)*KP + 32*kk + 8*q], ua);
        ld8(&kn_p[(16*si+m)*KP + 32*kk + 8*q], ub);
        FragHL fa = mkfrag(ua), fb = mkfrag(ub);
        g = mfma16(fa.h, fb.h, g);
        g = mfma16(fa.h, fb.l, g);
        g = mfma16(fa.l, fb.h, g);
      }
      #pragma unroll
      for (int reg=0; reg<4; ++reg)
        Gt[(16*ti + 4*q + reg)*GS + 16*si + m] = g[reg];
    }

    // ---- Phase A: vp0 = M * Kn^T ----
    {
      f32x4 v0 = (f32x4){0.f,0.f,0.f,0.f};
      f32x4 v1 = (f32x4){0.f,0.f,0.f,0.f};
      uint32_t* mybase = &msc[wv*MSW];
      #pragma unroll
      for (int kk=0; kk<4; ++kk) {
        #pragma unroll
        for (int c2=0; c2<2; ++c2) {
          const int ct = 2*kk + c2;
          #pragma unroll
          for (int reg=0; reg<4; ++reg)
            mybase[(4*q+reg)*MSR + 16*c2 + m] = packhl(Macc[ct][reg]);
        }
        uint32_t ua[8], ub[8];
        ld8(&mybase[m*MSR + 8*q], ua);
        FragHL fa = mkfrag(ua);
        ld8(&kn_p[m*KP + 32*kk + 8*q], ub);
        FragHL fb = mkfrag(ub);
        v0 = mfma16(fa.h, fb.h, v0);
        v0 = mfma16(fa.h, fb.l, v0);
        v0 = mfma16(fa.l, fb.h, v0);
        ld8(&kn_p[(16+m)*KP + 32*kk + 8*q], ub);
        fb = mkfrag(ub);
        v1 = mfma16(fa.h, fb.h, v1);
        v1 = mfma16(fa.h, fb.l, v1);
        v1 = mfma16(fa.l, fb.h, v1);
      }
      *reinterpret_cast<f32x4*>(&vpd[m*VS + 16*wv + 4*q]) = v0;
      *reinterpret_cast<f32x4*>(&vpd[(16+m)*VS + 16*wv + 4*q]) = v1;
    }
    __syncthreads();                       // B1: vpd(vp0) + Gt ready

    // ---- serial d-recurrence (wave 0, fp32, register-resident) ----
    if (wv==0) {
      float ad0[CC], ad1[CC], gr[CC];
      #pragma unroll
      for (int t=0;t<CC;++t) gr[t] = Gt[t*GS + (lane&31)];
      #pragma unroll
      for (int t=0;t<CC;++t) {
        const float nrm = nrm_l[t];
        const uint32_t u0 = kn_p[t*KP + lane];
        const uint32_t u1 = kn_p[t*KP + 64 + lane];
        const float kn0 = unpackhl(u0);
        const float kn1 = unpackhl(u1);
        float a0e = nrm*kn0 - vpd[t*VS + lane];
        float a1e = nrm*kn1 - vpd[t*VS + 64 + lane];
        float a0o = 0.f, a1o = 0.f;
        #pragma unroll
        for (int s=0; s<t; ++s) {
          const float g = rdlane(gr[t], s);
          if (s & 1) { a0o -= g*ad0[s]; a1o -= g*ad1[s]; }
          else       { a0e -= g*ad0[s]; a1e -= g*ad1[s]; }
        }
        const float acc0 = a0e + a0o;
        const float acc1 = a1e + a1o;
        float sq = acc0*acc0 + acc1*acc1;
        sq += __shfl_xor(sq,32); sq += __shfl_xor(sq,16); sq += __shfl_xor(sq,8);
        sq += __shfl_xor(sq,4);  sq += __shfl_xor(sq,2);  sq += __shfl_xor(sq,1);
        if (ch==NCH-1 && t==CC-1) {
          read_ws[b*Hn + lane]      = nrm*(nrm*kn0 - acc0);
          read_ws[b*Hn + 64 + lane] = nrm*(nrm*kn1 - acc1);
        } else {
          const float at = (sqrtf(sq) >= 0.4f*nrm) ? LAMBDA_ : 0.f;
          ad0[t] = at*acc0; ad1[t] = at*acc1;
          vpd[t*VS + lane]      = ad0[t];
          vpd[t*VS + 64 + lane] = ad1[t];
        }
      }
    }
    __syncthreads();                       // B2: ad ready
    if (ch==NCH-1) break;

    // ---- Phase E: M += AD^T * Kn ----
    {
      uint32_t ap[8];
      #pragma unroll
      for (int j=0;j<8;++j)
        ap[j] = packhl(vpd[(8*q+j)*VS + 16*wv + m]);
      FragHL fa = mkfrag(ap);
      #pragma unroll
      for (int ct=0; ct<8; ++ct) {
        uint32_t bu[8];
        #pragma unroll
        for (int j=0;j<8;++j)
          bu[j] = kn_p[(8*q+j)*KP + 16*ct + m];
        FragHL fb = mkfrag(bu);
        Macc[ct] = mfma16(fa.h, fb.h, Macc[ct]);
        Macc[ct] = mfma16(fa.h, fb.l, Macc[ct]);
        Macc[ct] = mfma16(fa.l, fb.h, Macc[ct]);
      }
    }
    __syncthreads();                       // B3: kn_p free to overwrite

    // ---- stage prefetched chunk ch+1 ----
    if (tid < 256) {
      const int t = tid>>3, g = tid&7;
      uint4* dst = reinterpret_cast<uint4*>(&kn_p[t*KP + g*16]);
      dst[0]=pfa; dst[1]=pfb; dst[2]=pfc; dst[3]=pfd;
    }
    if (tid >= 256 && tid < 256+CC) nrm_l[tid-256] = pfn;
    __syncthreads();                       // B4
  }
}

// ---------------------------------------------------------------------------
// Phase 3a: o1 = read @ rp_w^T + rp_b
// ---------------------------------------------------------------------------
__global__ __launch_bounds__(128) void p3a(
    const float* __restrict__ read_ws, const float* __restrict__ rp_w,
    const float* __restrict__ rp_b, float* __restrict__ o1_ws)
{
  __shared__ float rd[128];
  const int b = blockIdx.x, t = threadIdx.x;
  rd[t] = read_ws[b*Hn + t];
  __syncthreads();
  float acc = rp_b[t];
  const float* wr = rp_w + t*Hn;
  #pragma unroll 4
  for (int i = 0; i < Hn; ++i) acc += rd[i]*wr[i];
  o1_ws[b*Hn + t] = acc;
}

// ---------------------------------------------------------------------------
// Phase 3b: out = o1 @ out_w^T + out_b
// ---------------------------------------------------------------------------
__global__ __launch_bounds__(256) void p3b(
    const float* __restrict__ o1_ws, const float* __restrict__ out_w,
    const float* __restrict__ out_b, float* __restrict__ out)
{
  __shared__ __align__(16) float o1[8192];       // [64][128]
  const int tid = threadIdx.x;
  #pragma unroll
  for (int c = 0; c < 32; ++c) o1[c*256+tid] = o1_ws[c*256+tid];
  __syncthreads();
  const int v = blockIdx.x*256 + tid;            // 125*256 == 32000
  float acc[64];
  const float ob = out_b[v];
  #pragma unroll
  for (int bb = 0; bb < 64; ++bb) acc[bb] = ob;
  const float4* wrow = reinterpret_cast<const float4*>(out_w + (size_t)v*Hn);
  #pragma unroll 1
  for (int r4 = 0; r4 < 32; ++r4) {
    const float4 wv = wrow[r4];
    #pragma unroll
    for (int bb = 0; bb < 64; ++bb) {
      const float4 ov = *reinterpret_cast<const float4*>(&o1[bb*Hn + r4*4]);
      acc[bb] += wv.x*ov.x + wv.y*ov.y + wv.z*ov.z + wv.w*ov.w;
    }
  }
  #pragma unroll
  for (int bb = 0; bb < 64; ++bb) out[(size_t)bb*Vn + v] = acc[bb];
}

// ---------------------------------------------------------------------------
extern "C" void kernel_launch(void* const* d_in, const int* in_sizes, int n_in,
                              void* d_out, int out_size, void* d_ws, size_t ws_size,
                              hipStream_t stream)
{
  const int*   seq     = (const int*)  d_in[0];
  const float* embed_w = (const float*)d_in[1];
  const float* ff_w1   = (const float*)d_in[2];
  const float* ff_b1   = (const float*)d_in[3];
  const float* ff_w2   = (const float*)d_in[4];
  const float* ff_b2   = (const float*)d_in[5];
  const float* ln_g    = (const float*)d_in[6];
  const float* ln_b    = (const float*)d_in[7];
  const float* kp_w    = (const float*)d_in[8];
  const float* rp_w    = (const float*)d_in[9];
  const float* rp_b    = (const float*)d_in[10];
  const float* out_w   = (const float*)d_in[11];
  const float* out_b   = (const float*)d_in[12];

  float* ws          = (float*)d_ws;
  uint32_t* knp_all  = (uint32_t*)ws;                 // B*L*H u32 (packed hi/lo)
  float* norm_all    = ws + (size_t)Bn*Ln*Hn;         // B*L
  float* read_ws     = norm_all + (size_t)Bn*Ln;      // B*H
  float* o1_ws       = read_ws + Bn*Hn;               // B*H
  uint32_t* wp       = (uint32_t*)(o1_ws + Bn*Hn);    // 81920 u32 packed weights

  p0_pack<<<dim3(160), dim3(256), 0, stream>>>(ff_w1, ff_w2, kp_w, wp);
  p1_fused<<<dim3(2048), dim3(256), 0, stream>>>(
      seq, embed_w, wp, ff_b1, ff_b2, ln_g, ln_b, knp_all, norm_all);
  p2_scan<<<dim3(64), dim3(512), 0, stream>>>(knp_all, norm_all, read_ws);
  p3a<<<dim3(64), dim3(128), 0, stream>>>(read_ws, rp_w, rp_b, o1_ws);
  p3b<<<dim3(125), dim3(256), 0, stream>>>(o1_ws, out_w, out_b, (float*)d_out);
}